// Round 1
// baseline (595.013 us; speedup 1.0000x reference)
//
#include <hip/hip_runtime.h>

typedef unsigned short u16;
typedef __attribute__((ext_vector_type(8))) short bf16x8;   // 8 bf16 = 4 VGPRs
typedef __attribute__((ext_vector_type(4))) float f32x4;

#define MFMA(a,b,c) __builtin_amdgcn_mfma_f32_16x16x32_bf16((a),(b),(c),0,0,0)

// Problem dims
#define BB 2
#define SS 4096
#define NN 256
#define HH 8
#define QQ 64
#define ZZ 512

__device__ __forceinline__ u16 f2bf(float f){           // RNE fp32->bf16 (finite data)
  unsigned int u = __float_as_uint(f);
  u += 0x7fffu + ((u >> 16) & 1u);
  return (u16)(u >> 16);
}

__device__ __forceinline__ f32x4 fzero(){ f32x4 z = {0.f,0.f,0.f,0.f}; return z; }

__device__ __forceinline__ bf16x8 cvt8(const float* __restrict__ p){
  union { bf16x8 v; u16 u[8]; } t;
  #pragma unroll
  for (int j = 0; j < 8; j++) t.u[j] = f2bf(p[j]);
  return t.v;
}

// ---------------- prep: X -> bf16 ----------------
__global__ void cast_x_kernel(const float* __restrict__ in, u16* __restrict__ out){
  int i = blockIdx.x * blockDim.x + threadIdx.x;
  float4 v = ((const float4*)in)[i];
  ushort4 o;
  o.x = f2bf(v.x); o.y = f2bf(v.y); o.z = f2bf(v.z); o.w = f2bf(v.w);
  ((ushort4*)out)[i] = o;
}

// ---------------- prep: transpose + cast (batched, 32x32 LDS tiles) ----------------
// in: [batch][R][C] fp32  ->  out: [batch][C][R] bf16
__global__ void transpose_cast_kernel(const float* __restrict__ in, u16* __restrict__ out,
                                      int R, int C){
  __shared__ float t[32][33];
  const size_t base = (size_t)blockIdx.z * R * C;
  const float* ip = in + base;
  u16* op = out + base;
  int c0 = blockIdx.x * 32, r0 = blockIdx.y * 32;
  int c = threadIdx.x & 31, r = threadIdx.x >> 5;      // 32 x 8
  #pragma unroll
  for (int rr = 0; rr < 32; rr += 8)
    t[r + rr][c] = ip[(size_t)(r0 + r + rr) * C + (c0 + c)];
  __syncthreads();
  #pragma unroll
  for (int rr = 0; rr < 32; rr += 8)
    op[(size_t)(c0 + r + rr) * R + (r0 + c)] = f2bf(t[c][r + rr]);
}

// ---------------- XM = (X @ M_h)/64 -> Qb bf16 [B,H,S,N] ----------------
// grid (S/64, B*H), 256 thr. Mt is [H][m][n] (pre-transposed) so B-frags are contiguous.
__global__ __launch_bounds__(256) void xm_kernel(const float* __restrict__ X,
                                                 const u16* __restrict__ Mt,
                                                 u16* __restrict__ Qb){
  int bh = blockIdx.y, b = bh >> 3, h = bh & 7;
  int sbase = blockIdx.x * 64;
  int lane = threadIdx.x & 63, w = threadIdx.x >> 6;
  int lr = lane & 15, g = lane >> 4, lk = g * 8;

  const float* Ap = X + ((size_t)b * SS + sbase + w * 16 + lr) * NN;
  const u16* Bp = Mt + (size_t)h * NN * NN;

  bf16x8 afr[8];
  #pragma unroll
  for (int ks = 0; ks < 8; ks++) afr[ks] = cvt8(Ap + lk + 32 * ks);

  f32x4 acc[16];
  #pragma unroll
  for (int n = 0; n < 16; n++) acc[n] = fzero();

  for (int n = 0; n < 16; n++){
    const u16* bp = Bp + (size_t)(n * 16 + lr) * NN + lk;
    #pragma unroll
    for (int ks = 0; ks < 8; ks++)
      acc[n] = MFMA(afr[ks], *(const bf16x8*)(bp + 32 * ks), acc[n]);
  }
  u16* Op = Qb + ((size_t)bh * SS + sbase + w * 16) * NN;
  #pragma unroll
  for (int n = 0; n < 16; n++)
    #pragma unroll
    for (int r = 0; r < 4; r++)
      Op[(size_t)(g * 4 + r) * NN + n * 16 + lr] = f2bf(acc[n][r] * 0.015625f); // /64 folded
}

// ---------------- V^T: Vt[b,h][q][t] = (X @ Wv_h)^T bf16 ----------------
// grid (S/256, B*H), 256 thr. Wvt is [H][q][n] (pre-transposed).
__global__ __launch_bounds__(256) void vt_kernel(const float* __restrict__ X,
                                                 const u16* __restrict__ Wvt,
                                                 u16* __restrict__ Vt){
  int bh = blockIdx.y, b = bh >> 3, h = bh & 7;
  int tbase = blockIdx.x * 256;
  int lane = threadIdx.x & 63, w = threadIdx.x >> 6;
  int lr = lane & 15, g = lane >> 4, lk = g * 8;

  const u16* Ap = Wvt + ((size_t)h * QQ + w * 16 + lr) * NN + lk;
  bf16x8 afr[8];
  #pragma unroll
  for (int ks = 0; ks < 8; ks++) afr[ks] = *(const bf16x8*)(Ap + 32 * ks);

  f32x4 acc[16];
  #pragma unroll
  for (int n = 0; n < 16; n++) acc[n] = fzero();

  for (int n = 0; n < 16; n++){
    const float* bp = X + ((size_t)b * SS + tbase + n * 16 + lr) * NN + lk;
    #pragma unroll
    for (int ks = 0; ks < 8; ks++)
      acc[n] = MFMA(afr[ks], cvt8(bp + 32 * ks), acc[n]);
  }
  u16* Op = Vt + ((size_t)bh * QQ + w * 16 + g * 4) * SS + tbase;
  #pragma unroll
  for (int n = 0; n < 16; n++)
    #pragma unroll
    for (int r = 0; r < 4; r++)
      Op[(size_t)r * SS + n * 16 + lr] = f2bf(acc[n][r]);
}

// ---------------- fused flash attention ----------------
// grid (S/64, B*H), 256 thr (4 waves). Wave w owns q-rows [qbase+16w, +16).
__global__ __launch_bounds__(256, 2) void attn_kernel(const u16* __restrict__ Qb,
                                                      const u16* __restrict__ Kb,
                                                      const u16* __restrict__ Vt,
                                                      u16* __restrict__ Zc){
  int bh = blockIdx.y, b = bh >> 3, h = bh & 7;
  int qbase = blockIdx.x * 64;
  int tid = threadIdx.x, lane = tid & 63, w = tid >> 6;
  int lr = lane & 15, g = lane >> 4, lk = g * 8;

  __shared__ u16 k_lds[64 * 256];          // 32 KB, XOR-swizzled rows of 512B
  __shared__ u16 v_lds[64 * 64];           // 8 KB, [vc][key], XOR-swizzled rows of 128B
  __shared__ u16 p_lds[4][16][72];         // per-wave P re-fragmentation, +8 pad

  // Q fragments: register-resident across the whole KV loop (scale 1/64 pre-folded)
  bf16x8 qfr[8];
  const u16* Qp = Qb + ((size_t)bh * SS + qbase + w * 16 + lr) * NN + lk;
  #pragma unroll
  for (int ks = 0; ks < 8; ks++) qfr[ks] = *(const bf16x8*)(Qp + 32 * ks);

  f32x4 o[4];
  #pragma unroll
  for (int n = 0; n < 4; n++) o[n] = fzero();
  float m[4], l[4];
  #pragma unroll
  for (int r = 0; r < 4; r++){ m[r] = -1e30f; l[r] = 0.f; }

  const char* Kg = (const char*)(Kb + (size_t)b * SS * NN);
  const u16* Vg = Vt + (size_t)bh * QQ * SS;

  for (int kt = 0; kt < SS / 64; ++kt){
    int kbase = kt * 64;
    __syncthreads();                                   // prior tile's LDS reads done
    // stage K tile: 64 rows x 512B; LDS dest XOR-swizzled so frag reads are conflict-free
    {
      const char* src = Kg + (size_t)kbase * 512;
      #pragma unroll
      for (int c = 0; c < 8; c++){
        int off = (c * 256 + tid) * 16;
        uint4 v = *(const uint4*)(src + off);
        *(uint4*)((char*)k_lds + (off ^ (((off >> 9) & 7) << 4))) = v;
      }
      // stage V tile: [64 vc][64 keys] from Vt[vc][kbase..]
      #pragma unroll
      for (int c = 0; c < 2; c++){
        int idx = c * 256 + tid;
        int vc = idx >> 3, koff = (idx & 7) * 16;
        uint4 v = *(const uint4*)((const char*)(Vg + (size_t)vc * SS + kbase) + koff);
        int off = vc * 128 + koff;
        *(uint4*)((char*)v_lds + (off ^ ((vc & 7) << 4))) = v;
      }
    }
    __syncthreads();                                   // tile staged (drains vmcnt)

    // scores: 16 q-rows x 64 keys, K = 256
    f32x4 sa[4];
    #pragma unroll
    for (int n = 0; n < 4; n++) sa[n] = fzero();
    #pragma unroll
    for (int n = 0; n < 4; n++){
      int row = n * 16 + lr;
      int rb = row * 512, sw = (row & 7) << 4;
      #pragma unroll
      for (int ks = 0; ks < 8; ks++){
        bf16x8 kfr = *(const bf16x8*)((const char*)k_lds + ((rb + lk * 2 + 64 * ks) ^ sw));
        sa[n] = MFMA(qfr[ks], kfr, sa[n]);
      }
    }

    // online softmax (wave-parallel row reduce over the 16 lanes sharing g)
    float fs[4];
    #pragma unroll
    for (int r = 0; r < 4; r++){
      float pm = fmaxf(fmaxf(sa[0][r], sa[1][r]), fmaxf(sa[2][r], sa[3][r]));
      #pragma unroll
      for (int d = 1; d < 16; d <<= 1) pm = fmaxf(pm, __shfl_xor(pm, d));
      float mn = fmaxf(m[r], pm);
      fs[r] = __expf(m[r] - mn);
      m[r] = mn;
    }
    #pragma unroll
    for (int n = 0; n < 4; n++)
      #pragma unroll
      for (int r = 0; r < 4; r++){
        float p = __expf(sa[n][r] - m[r]);
        sa[n][r] = p;
        p_lds[w][g * 4 + r][n * 16 + lr] = f2bf(p);    // D-layout -> [qrow][key]
      }
    #pragma unroll
    for (int r = 0; r < 4; r++){
      float ps = (sa[0][r] + sa[1][r]) + (sa[2][r] + sa[3][r]);
      #pragma unroll
      for (int d = 1; d < 16; d <<= 1) ps += __shfl_xor(ps, d);
      l[r] = l[r] * fs[r] + ps;
      #pragma unroll
      for (int n = 0; n < 4; n++) o[n][r] *= fs[r];
    }

    // cross-lane LDS RAW within the wave: drain ds queue, pin ordering (rule 18)
    asm volatile("s_waitcnt lgkmcnt(0)" ::: "memory");
    __builtin_amdgcn_sched_barrier(0);

    // O += P @ V
    #pragma unroll
    for (int kk = 0; kk < 2; kk++){
      bf16x8 pfr = *(const bf16x8*)(&p_lds[w][lr][lk + 32 * kk]);
      #pragma unroll
      for (int n = 0; n < 4; n++){
        int vc = n * 16 + lr;
        int off = vc * 128 + 64 * kk + lk * 2;
        bf16x8 vfr = *(const bf16x8*)((const char*)v_lds + (off ^ ((vc & 7) << 4)));
        o[n] = MFMA(pfr, vfr, o[n]);
      }
    }
  }

  // epilogue: normalize, write Zc[b,s, h*64 + q] bf16
  u16* Op = Zc + ((size_t)b * SS + qbase + w * 16 + g * 4) * (HH * QQ) + h * QQ;
  #pragma unroll
  for (int r = 0; r < 4; r++){
    float inv = 1.0f / l[r];
    #pragma unroll
    for (int n = 0; n < 4; n++)
      Op[(size_t)r * (HH * QQ) + n * 16 + lr] = f2bf(o[n][r] * inv);
  }
}

// ---------------- out = Zc @ W0 (fp32 out) ----------------
// grid (B*S/64, Z/128), 256 thr. W0t is [z][c] pre-transposed bf16.
__global__ __launch_bounds__(256) void out_kernel(const u16* __restrict__ Zc,
                                                  const u16* __restrict__ W0t,
                                                  float* __restrict__ out){
  int rbase = blockIdx.x * 64, cbase = blockIdx.y * 128;
  int lane = threadIdx.x & 63, w = threadIdx.x >> 6;
  int lr = lane & 15, g = lane >> 4, lk = g * 8;

  const u16* Ap = Zc + (size_t)(rbase + w * 16 + lr) * ZZ + lk;
  f32x4 acc[8];
  #pragma unroll
  for (int n = 0; n < 8; n++) acc[n] = fzero();

  for (int ks = 0; ks < 16; ks++){
    bf16x8 afr = *(const bf16x8*)(Ap + 32 * ks);
    #pragma unroll
    for (int n = 0; n < 8; n++){
      const u16* bp = W0t + (size_t)(cbase + n * 16 + lr) * ZZ + lk + 32 * ks;
      acc[n] = MFMA(afr, *(const bf16x8*)bp, acc[n]);
    }
  }
  float* Op = out + (size_t)(rbase + w * 16 + g * 4) * ZZ + cbase;
  #pragma unroll
  for (int n = 0; n < 8; n++)
    #pragma unroll
    for (int r = 0; r < 4; r++)
      Op[(size_t)r * ZZ + n * 16 + lr] = acc[n][r];
}

extern "C" void kernel_launch(void* const* d_in, const int* in_sizes, int n_in,
                              void* d_out, int out_size, void* d_ws, size_t ws_size,
                              hipStream_t stream){
  (void)in_sizes; (void)n_in; (void)out_size; (void)ws_size;
  const float* X  = (const float*)d_in[0];   // [B,S,N]
  const float* M  = (const float*)d_in[1];   // [H,N,N]
  const float* Wv = (const float*)d_in[2];   // [H,N,Q]
  const float* W0 = (const float*)d_in[3];   // [H*Q,Z]
  float* out = (float*)d_out;                // [B,S,Z] fp32

  char* ws = (char*)d_ws;
  size_t off = 0;
  auto alloc = [&](size_t bytes) -> void* {
    void* p = ws + off; off += (bytes + 255) & ~(size_t)255; return p;
  };
  u16* Kb  = (u16*)alloc((size_t)BB * SS * NN * 2);        // X as bf16
  u16* Qb  = (u16*)alloc((size_t)BB * HH * SS * NN * 2);   // (X@M_h)/64 bf16
  u16* Vtb = (u16*)alloc((size_t)BB * HH * QQ * SS * 2);   // V transposed bf16
  u16* Mt  = (u16*)alloc((size_t)HH * NN * NN * 2);
  u16* Wvt = (u16*)alloc((size_t)HH * QQ * NN * 2);
  u16* W0t = (u16*)alloc((size_t)ZZ * ZZ * 2);
  u16* Zc  = (u16*)alloc((size_t)BB * SS * HH * QQ * 2);

  cast_x_kernel<<<dim3(BB * SS * NN / 1024), dim3(256), 0, stream>>>(X, Kb);
  transpose_cast_kernel<<<dim3(NN/32, NN/32, HH), dim3(256), 0, stream>>>(M,  Mt,  NN, NN);
  transpose_cast_kernel<<<dim3(QQ/32, NN/32, HH), dim3(256), 0, stream>>>(Wv, Wvt, NN, QQ);
  transpose_cast_kernel<<<dim3(ZZ/32, ZZ/32, 1),  dim3(256), 0, stream>>>(W0, W0t, ZZ, ZZ);
  xm_kernel<<<dim3(SS/64, BB*HH),  dim3(256), 0, stream>>>(X, Mt, Qb);
  vt_kernel<<<dim3(SS/256, BB*HH), dim3(256), 0, stream>>>(X, Wvt, Vtb);
  attn_kernel<<<dim3(SS/64, BB*HH), dim3(256), 0, stream>>>(Qb, Kb, Vtb, Zc);
  out_kernel<<<dim3(BB*SS/64, ZZ/128), dim3(256), 0, stream>>>(Zc, W0t, out);
}

// Round 2
// 426.258 us; speedup vs baseline: 1.3959x; 1.3959x over previous
//
#include <hip/hip_runtime.h>

typedef unsigned short u16;
typedef unsigned long long uptr;
typedef __attribute__((ext_vector_type(8))) short bf16x8;   // 8 bf16 = 4 VGPRs
typedef __attribute__((ext_vector_type(4))) float f32x4;
typedef __attribute__((ext_vector_type(16))) float f32x16;

#define MFMA16(a,b,c) __builtin_amdgcn_mfma_f32_16x16x32_bf16((a),(b),(c),0,0,0)
#define MFMA32(a,b,c) __builtin_amdgcn_mfma_f32_32x32x16_bf16((a),(b),(c),0,0,0)

// Problem dims
#define BB 2
#define SS 4096
#define NN 256
#define HH 8
#define QQ 64
#define ZZ 512

__device__ __forceinline__ u16 f2bf(float f){           // RNE fp32->bf16 (finite data)
  unsigned int u = __float_as_uint(f);
  u += 0x7fffu + ((u >> 16) & 1u);
  return (u16)(u >> 16);
}

__device__ __forceinline__ f32x4 fzero(){ f32x4 z = {0.f,0.f,0.f,0.f}; return z; }

__device__ __forceinline__ f32x16 zero16(){
  f32x16 z;
  #pragma unroll
  for (int i = 0; i < 16; i++) z[i] = 0.f;
  return z;
}

__device__ __forceinline__ unsigned pkbf(float a, float b){  // low16=bf16(a), high16=bf16(b)
  unsigned r;
  asm("v_cvt_pk_bf16_f32 %0, %1, %2" : "=v"(r) : "v"(a), "v"(b));
  return r;
}

__device__ __forceinline__ bf16x8 cvt8(const float* __restrict__ p){
  union { bf16x8 v; u16 u[8]; } t;
  #pragma unroll
  for (int j = 0; j < 8; j++) t.u[j] = f2bf(p[j]);
  return t.v;
}

// async global->LDS, 16B per lane. LDS dest is wave-uniform base + lane*16;
// global src is per-lane (pre-swizzled for conflict-free ds_reads, m173 pattern).
typedef __attribute__((address_space(1))) const void gas_void;
typedef __attribute__((address_space(3))) void las_void;
__device__ __forceinline__ void gload16(const void* g, void* l){
  // generic LDS pointer: low 32 bits = LDS offset on amdgcn
  __builtin_amdgcn_global_load_lds((gas_void*)(uptr)g,
                                   (las_void*)(uptr)(unsigned)(uptr)l, 16, 0, 0);
}

// ---------------- prep: X -> bf16 ----------------
__global__ void cast_x_kernel(const float* __restrict__ in, u16* __restrict__ out){
  int i = blockIdx.x * blockDim.x + threadIdx.x;
  float4 v = ((const float4*)in)[i];
  ushort4 o;
  o.x = f2bf(v.x); o.y = f2bf(v.y); o.z = f2bf(v.z); o.w = f2bf(v.w);
  ((ushort4*)out)[i] = o;
}

// ---------------- prep: transpose + cast (batched, 32x32 LDS tiles) ----------------
__global__ void transpose_cast_kernel(const float* __restrict__ in, u16* __restrict__ out,
                                      int R, int C){
  __shared__ float t[32][33];
  const size_t base = (size_t)blockIdx.z * R * C;
  const float* ip = in + base;
  u16* op = out + base;
  int c0 = blockIdx.x * 32, r0 = blockIdx.y * 32;
  int c = threadIdx.x & 31, r = threadIdx.x >> 5;      // 32 x 8
  #pragma unroll
  for (int rr = 0; rr < 32; rr += 8)
    t[r + rr][c] = ip[(size_t)(r0 + r + rr) * C + (c0 + c)];
  __syncthreads();
  #pragma unroll
  for (int rr = 0; rr < 32; rr += 8)
    op[(size_t)(c0 + r + rr) * R + (r0 + c)] = f2bf(t[c][r + rr]);
}

// ---------------- XM = (X @ M_h) * (1/64)*log2(e) -> Qb bf16 [B,H,S,N] ----------------
// scale folds the softmax 1/q AND log2(e) so attn can use exp2 directly.
__global__ __launch_bounds__(256) void xm_kernel(const float* __restrict__ X,
                                                 const u16* __restrict__ Mt,
                                                 u16* __restrict__ Qb){
  const float QSCALE = 0.015625f * 1.4426950408889634f;
  int bh = blockIdx.y, b = bh >> 3, h = bh & 7;
  int sbase = blockIdx.x * 64;
  int lane = threadIdx.x & 63, w = threadIdx.x >> 6;
  int lr = lane & 15, g = lane >> 4, lk = g * 8;

  const float* Ap = X + ((size_t)b * SS + sbase + w * 16 + lr) * NN;
  const u16* Bp = Mt + (size_t)h * NN * NN;

  bf16x8 afr[8];
  #pragma unroll
  for (int ks = 0; ks < 8; ks++) afr[ks] = cvt8(Ap + lk + 32 * ks);

  f32x4 acc[16];
  #pragma unroll
  for (int n = 0; n < 16; n++) acc[n] = fzero();

  for (int n = 0; n < 16; n++){
    const u16* bp = Bp + (size_t)(n * 16 + lr) * NN + lk;
    #pragma unroll
    for (int ks = 0; ks < 8; ks++)
      acc[n] = MFMA16(afr[ks], *(const bf16x8*)(bp + 32 * ks), acc[n]);
  }
  u16* Op = Qb + ((size_t)bh * SS + sbase + w * 16) * NN;
  #pragma unroll
  for (int n = 0; n < 16; n++)
    #pragma unroll
    for (int r = 0; r < 4; r++)
      Op[(size_t)(g * 4 + r) * NN + n * 16 + lr] = f2bf(acc[n][r] * QSCALE);
}

// ---------------- V^T: Vt[b,h][q][t] = (X @ Wv_h)^T bf16 ----------------
__global__ __launch_bounds__(256) void vt_kernel(const float* __restrict__ X,
                                                 const u16* __restrict__ Wvt,
                                                 u16* __restrict__ Vt){
  int bh = blockIdx.y, b = bh >> 3, h = bh & 7;
  int tbase = blockIdx.x * 256;
  int lane = threadIdx.x & 63, w = threadIdx.x >> 6;
  int lr = lane & 15, g = lane >> 4, lk = g * 8;

  const u16* Ap = Wvt + ((size_t)h * QQ + w * 16 + lr) * NN + lk;
  bf16x8 afr[8];
  #pragma unroll
  for (int ks = 0; ks < 8; ks++) afr[ks] = *(const bf16x8*)(Ap + 32 * ks);

  f32x4 acc[16];
  #pragma unroll
  for (int n = 0; n < 16; n++) acc[n] = fzero();

  for (int n = 0; n < 16; n++){
    const float* bp = X + ((size_t)b * SS + tbase + n * 16 + lr) * NN + lk;
    #pragma unroll
    for (int ks = 0; ks < 8; ks++)
      acc[n] = MFMA16(afr[ks], cvt8(bp + 32 * ks), acc[n]);
  }
  u16* Op = Vt + ((size_t)bh * QQ + w * 16 + g * 4) * SS + tbase;
  #pragma unroll
  for (int n = 0; n < 16; n++)
    #pragma unroll
    for (int r = 0; r < 4; r++)
      Op[(size_t)r * SS + n * 16 + lr] = f2bf(acc[n][r]);
}

// ---------------- fused flash attention, 32x32 swapped-QK^T (m214 structure) ----------
// 4 waves x 32 q-rows = 128 q/block. grid: 512 blocks (1D, XCD-grouped by bh).
// Per lane: q = lane&31 for P (swapped QK^T makes softmax lane-local);
// K/V tiles in XOR-swizzled LDS staged via global_load_lds w/ pre-swizzled source.
__global__ __launch_bounds__(256, 2) void attn_kernel(const u16* __restrict__ Qb,
                                                      const u16* __restrict__ Kb,
                                                      const u16* __restrict__ Vt,
                                                      u16* __restrict__ Zc){
  // XCD-aware decode: blocks sharing bh land on the same XCD (K/V L2 locality)
  int lid = blockIdx.x;
  int bh = (lid & 7) | (((lid >> 3) & 1) << 3);
  int qi = lid >> 4;
  int b = bh >> 3, h = bh & 7;

  int tid = threadIdx.x, lane = tid & 63, w = tid >> 6;
  int l31 = lane & 31, hi = lane >> 5;
  int hi16 = hi * 16;                 // byte offset of this half's k-slice
  int sw = (lane & 7) << 4;           // XOR bank swizzle (row&7 == lane&7 for both tiles)

  __shared__ u16 k_lds[64 * 256];     // 32 KB: K rows [key][n], swizzled
  __shared__ u16 v_lds[64 * 64];      // 8 KB: Vt rows [vq][key], swizzled
  __shared__ float fs_lds[4][32];     // per-wave rescale broadcast

  int qrow = qi * 128 + w * 32 + l31;

  // Q fragments register-resident: B-operand of swapped QK^T (16 x bf16x8 = 64 VGPR)
  const u16* Qp = Qb + ((size_t)bh * SS + qrow) * NN + hi * 8;
  bf16x8 qfr[16];
  #pragma unroll
  for (int ks = 0; ks < 16; ks++) qfr[ks] = *(const bf16x8*)(Qp + ks * 16);

  f32x16 o0 = zero16(), o1 = zero16();
  float m = -1e30f, l = 0.f;

  const char* Kg = (const char*)(Kb + (size_t)b * SS * NN);
  const char* Vg = (const char*)(Vt + (size_t)bh * QQ * SS);

  // staging source offsets (loop-invariant; inverse-swizzled so LDS-linear DMA
  // lands data where the swizzled ds_reads expect it)
  int koffK[8], koffV[2];
  #pragma unroll
  for (int c = 0; c < 8; c++){
    int x = c * 4096 + w * 1024 + lane * 16;
    koffK[c] = x ^ (((x >> 9) & 7) << 4);
  }
  #pragma unroll
  for (int c = 0; c < 2; c++){
    int x = c * 4096 + w * 1024 + lane * 16;   // x < 8192
    int vq = x >> 7, ko = x & 127;
    koffV[c] = vq * 8192 + (ko ^ ((vq & 7) << 4));
  }

  char* kl = (char*)k_lds;
  char* vl = (char*)v_lds;
  const char* ka0 = kl + l31 * 512;            // A-frag row bases (key tiles 0/1)
  const char* ka1 = kl + (32 + l31) * 512;
  const char* va0 = vl + l31 * 128;            // V B-frag row bases (vq tiles 0/1)
  const char* va1 = vl + (32 + l31) * 128;

#define PVSTEP(P, RB, OFF) {                                           \
    unsigned a_ = pkbf(P[RB+0], P[RB+1]);                              \
    unsigned b_ = pkbf(P[RB+2], P[RB+3]);                              \
    unsigned c_ = pkbf(P[RB+4], P[RB+5]);                              \
    unsigned d_ = pkbf(P[RB+6], P[RB+7]);                              \
    unsigned e_ = (unsigned)__shfl_xor((int)(hi ? a_ : c_), 32);       \
    unsigned f_ = (unsigned)__shfl_xor((int)(hi ? b_ : d_), 32);       \
    union { bf16x8 v; unsigned u[4]; } pu_;                            \
    pu_.u[0] = hi ? e_ : a_;  pu_.u[1] = hi ? f_ : b_;                 \
    pu_.u[2] = hi ? c_ : e_;  pu_.u[3] = hi ? d_ : f_;                 \
    bf16x8 vf0_ = *(const bf16x8*)(va0 + (OFF));                       \
    bf16x8 vf1_ = *(const bf16x8*)(va1 + (OFF));                       \
    o0 = MFMA32(pu_.v, vf0_, o0);                                      \
    o1 = MFMA32(pu_.v, vf1_, o1); }

  for (int kt = 0; kt < SS / 64; ++kt){
    // stage next tile (single-buffered: previous reads finished at loop-tail barrier)
    const char* kg = Kg + (size_t)kt * 32768;
    const char* vg = Vg + (size_t)kt * 128;
    #pragma unroll
    for (int c = 0; c < 8; c++) gload16(kg + koffK[c], kl + c * 4096 + w * 1024);
    #pragma unroll
    for (int c = 0; c < 2; c++) gload16(vg + koffV[c], vl + c * 4096 + w * 1024);
    __syncthreads();   // compiler drains vmcnt before barrier -> tile visible

    // swapped QK^T: p = K_tile * Q^T; lane holds P[q=l31][16 keys] per tile (crow layout)
    f32x16 p0 = zero16(), p1 = zero16();
    #pragma unroll
    for (int ks = 0; ks < 16; ks++){
      int off = (ks * 32 + hi16) ^ sw;
      bf16x8 k0 = *(const bf16x8*)(ka0 + off);
      bf16x8 k1 = *(const bf16x8*)(ka1 + off);
      p0 = MFMA32(k0, qfr[ks], p0);
      p1 = MFMA32(k1, qfr[ks], p1);
    }

    // online softmax in log2 domain (log2e folded into Q scale)
    float pm = fmaxf(p0[0], p0[1]);
    #pragma unroll
    for (int i = 2; i < 16; i++) pm = fmaxf(pm, p0[i]);
    #pragma unroll
    for (int i = 0; i < 16; i++) pm = fmaxf(pm, p1[i]);
    pm = fmaxf(pm, __shfl_xor(pm, 32));

    if (__any(pm > m + 8.0f)){           // defer-max (T13): rescale only when needed
      float mn = fmaxf(m, pm);
      float fs = exp2f(m - mn);
      m = mn; l *= fs;
      if (lane < 32) fs_lds[w][lane] = fs;
      f32x4 f0 = *(const f32x4*)&fs_lds[w][hi * 4];
      f32x4 f1 = *(const f32x4*)&fs_lds[w][8 + hi * 4];
      f32x4 f2 = *(const f32x4*)&fs_lds[w][16 + hi * 4];
      f32x4 f3 = *(const f32x4*)&fs_lds[w][24 + hi * 4];
      #pragma unroll
      for (int r = 0; r < 4; r++){
        o0[r]      *= f0[r]; o0[4 + r]  *= f1[r];
        o0[8 + r]  *= f2[r]; o0[12 + r] *= f3[r];
        o1[r]      *= f0[r]; o1[4 + r]  *= f1[r];
        o1[8 + r]  *= f2[r]; o1[12 + r] *= f3[r];
      }
    }

    #pragma unroll
    for (int i = 0; i < 16; i++){
      p0[i] = exp2f(p0[i] - m);
      p1[i] = exp2f(p1[i] - m);
    }
    float ps = 0.f;
    #pragma unroll
    for (int i = 0; i < 16; i++) ps += p0[i] + p1[i];
    ps += __shfl_xor(ps, 32);
    l += ps;

    // O += P @ V  (P->bf16 A-frags via cvt_pk + cross-half shfl, T12)
    PVSTEP(p0, 0, (0   + hi16) ^ sw)
    PVSTEP(p0, 8, (32  + hi16) ^ sw)
    PVSTEP(p1, 0, (64  + hi16) ^ sw)
    PVSTEP(p1, 8, (96  + hi16) ^ sw)

    __syncthreads();   // all waves done reading before next stage overwrites
  }
#undef PVSTEP

  // epilogue: normalize by 1/l (distributed via fs_lds), write Zc bf16
  float inv = 1.0f / l;
  if (lane < 32) fs_lds[w][lane] = inv;
  f32x4 f0 = *(const f32x4*)&fs_lds[w][hi * 4];
  f32x4 f1 = *(const f32x4*)&fs_lds[w][8 + hi * 4];
  f32x4 f2 = *(const f32x4*)&fs_lds[w][16 + hi * 4];
  f32x4 f3 = *(const f32x4*)&fs_lds[w][24 + hi * 4];
  u16* Op = Zc + ((size_t)b * SS + qi * 128 + w * 32) * (HH * QQ) + h * QQ;
  #pragma unroll
  for (int i = 0; i < 4; i++){
    f32x4 fv = (i == 0) ? f0 : (i == 1) ? f1 : (i == 2) ? f2 : f3;
    #pragma unroll
    for (int r = 0; r < 4; r++){
      int q = 8 * i + 4 * hi + r;
      u16* row = Op + (size_t)q * (HH * QQ);
      row[l31]      = f2bf(o0[4 * i + r] * fv[r]);
      row[32 + l31] = f2bf(o1[4 * i + r] * fv[r]);
    }
  }
}

// ---------------- out = Zc @ W0 (fp32 out) ----------------
__global__ __launch_bounds__(256) void out_kernel(const u16* __restrict__ Zc,
                                                  const u16* __restrict__ W0t,
                                                  float* __restrict__ out){
  int rbase = blockIdx.x * 64, cbase = blockIdx.y * 128;
  int lane = threadIdx.x & 63, w = threadIdx.x >> 6;
  int lr = lane & 15, g = lane >> 4, lk = g * 8;

  const u16* Ap = Zc + (size_t)(rbase + w * 16 + lr) * ZZ + lk;
  f32x4 acc[8];
  #pragma unroll
  for (int n = 0; n < 8; n++) acc[n] = fzero();

  for (int ks = 0; ks < 16; ks++){
    bf16x8 afr = *(const bf16x8*)(Ap + 32 * ks);
    #pragma unroll
    for (int n = 0; n < 8; n++){
      const u16* bp = W0t + (size_t)(cbase + n * 16 + lr) * ZZ + lk + 32 * ks;
      acc[n] = MFMA16(afr, *(const bf16x8*)bp, acc[n]);
    }
  }
  float* Op = out + (size_t)(rbase + w * 16 + g * 4) * ZZ + cbase;
  #pragma unroll
  for (int n = 0; n < 8; n++)
    #pragma unroll
    for (int r = 0; r < 4; r++)
      Op[(size_t)r * ZZ + n * 16 + lr] = acc[n][r];
}

extern "C" void kernel_launch(void* const* d_in, const int* in_sizes, int n_in,
                              void* d_out, int out_size, void* d_ws, size_t ws_size,
                              hipStream_t stream){
  (void)in_sizes; (void)n_in; (void)out_size; (void)ws_size;
  const float* X  = (const float*)d_in[0];   // [B,S,N]
  const float* M  = (const float*)d_in[1];   // [H,N,N]
  const float* Wv = (const float*)d_in[2];   // [H,N,Q]
  const float* W0 = (const float*)d_in[3];   // [H*Q,Z]
  float* out = (float*)d_out;                // [B,S,Z] fp32

  char* ws = (char*)d_ws;
  size_t off = 0;
  auto alloc = [&](size_t bytes) -> void* {
    void* p = ws + off; off += (bytes + 255) & ~(size_t)255; return p;
  };
  u16* Kb  = (u16*)alloc((size_t)BB * SS * NN * 2);        // X as bf16
  u16* Qb  = (u16*)alloc((size_t)BB * HH * SS * NN * 2);   // (X@M_h) scaled bf16
  u16* Vtb = (u16*)alloc((size_t)BB * HH * QQ * SS * 2);   // V transposed bf16
  u16* Mt  = (u16*)alloc((size_t)HH * NN * NN * 2);
  u16* Wvt = (u16*)alloc((size_t)HH * QQ * NN * 2);
  u16* W0t = (u16*)alloc((size_t)ZZ * ZZ * 2);
  u16* Zc  = (u16*)alloc((size_t)BB * SS * HH * QQ * 2);

  cast_x_kernel<<<dim3(BB * SS * NN / 1024), dim3(256), 0, stream>>>(X, Kb);
  transpose_cast_kernel<<<dim3(NN/32, NN/32, HH), dim3(256), 0, stream>>>(M,  Mt,  NN, NN);
  transpose_cast_kernel<<<dim3(QQ/32, NN/32, HH), dim3(256), 0, stream>>>(Wv, Wvt, NN, QQ);
  transpose_cast_kernel<<<dim3(ZZ/32, ZZ/32, 1),  dim3(256), 0, stream>>>(W0, W0t, ZZ, ZZ);
  xm_kernel<<<dim3(SS/64, BB*HH),  dim3(256), 0, stream>>>(X, Mt, Qb);
  vt_kernel<<<dim3(SS/256, BB*HH), dim3(256), 0, stream>>>(X, Wvt, Vtb);
  attn_kernel<<<dim3(512), dim3(256), 0, stream>>>(Qb, Kb, Vtb, Zc);
  out_kernel<<<dim3(BB*SS/64, ZZ/128), dim3(256), 0, stream>>>(Zc, W0t, out);
}

// Round 4
// 398.659 us; speedup vs baseline: 1.4925x; 1.0692x over previous
//
#include <hip/hip_runtime.h>

typedef unsigned short u16;
typedef unsigned long long uptr;
typedef __attribute__((ext_vector_type(8))) short bf16x8;   // 8 bf16 = 4 VGPRs
typedef __attribute__((ext_vector_type(4))) float f32x4;
typedef __attribute__((ext_vector_type(16))) float f32x16;

#define MFMA16(a,b,c) __builtin_amdgcn_mfma_f32_16x16x32_bf16((a),(b),(c),0,0,0)
#define MFMA32(a,b,c) __builtin_amdgcn_mfma_f32_32x32x16_bf16((a),(b),(c),0,0,0)

// Problem dims
#define BB 2
#define SS 4096
#define NN 256
#define HH 8
#define QQ 64
#define ZZ 512

__device__ __forceinline__ u16 f2bf(float f){           // RNE fp32->bf16 (finite data)
  unsigned int u = __float_as_uint(f);
  u += 0x7fffu + ((u >> 16) & 1u);
  return (u16)(u >> 16);
}

__device__ __forceinline__ f32x4 fzero(){ f32x4 z = {0.f,0.f,0.f,0.f}; return z; }

__device__ __forceinline__ f32x16 zero16(){
  f32x16 z;
  #pragma unroll
  for (int i = 0; i < 16; i++) z[i] = 0.f;
  return z;
}

__device__ __forceinline__ unsigned pkbf(float a, float b){  // low16=bf16(a), high16=bf16(b)
  unsigned r;
  asm("v_cvt_pk_bf16_f32 %0, %1, %2" : "=v"(r) : "v"(a), "v"(b));
  return r;
}

// async global->LDS, 16B per lane (dest = wave-uniform base + lane*16; src per-lane)
typedef __attribute__((address_space(1))) const void gas_void;
typedef __attribute__((address_space(3))) void las_void;
__device__ __forceinline__ void gload16(const void* g, void* l){
  __builtin_amdgcn_global_load_lds((gas_void*)(uptr)g,
                                   (las_void*)(uptr)(unsigned)(uptr)l, 16, 0, 0);
}

// ---------------- prep: X -> bf16 ----------------
__global__ void cast_x_kernel(const float* __restrict__ in, u16* __restrict__ out){
  int i = blockIdx.x * blockDim.x + threadIdx.x;
  float4 v = ((const float4*)in)[i];
  ushort4 o;
  o.x = f2bf(v.x); o.y = f2bf(v.y); o.z = f2bf(v.z); o.w = f2bf(v.w);
  ((ushort4*)out)[i] = o;
}

// ---------------- prep: transpose + cast (batched, 32x32 LDS tiles) ----------------
__global__ void transpose_cast_kernel(const float* __restrict__ in, u16* __restrict__ out,
                                      int R, int C){
  __shared__ float t[32][33];
  const size_t base = (size_t)blockIdx.z * R * C;
  const float* ip = in + base;
  u16* op = out + base;
  int c0 = blockIdx.x * 32, r0 = blockIdx.y * 32;
  int c = threadIdx.x & 31, r = threadIdx.x >> 5;      // 32 x 8
  #pragma unroll
  for (int rr = 0; rr < 32; rr += 8)
    t[r + rr][c] = ip[(size_t)(r0 + r + rr) * C + (c0 + c)];
  __syncthreads();
  #pragma unroll
  for (int rr = 0; rr < 32; rr += 8)
    op[(size_t)(c0 + r + rr) * R + (r0 + c)] = f2bf(t[c][r + rr]);
}

// ---------------- XM = (Xb @ M_h) * (1/64)*log2(e) -> Qb bf16 [B,H,S,N] ----------------
__global__ __launch_bounds__(256) void xm_kernel(const u16* __restrict__ Xb,
                                                 const u16* __restrict__ Mt,
                                                 u16* __restrict__ Qb){
  const float QSCALE = 0.015625f * 1.4426950408889634f;
  int bh = blockIdx.y, b = bh >> 3, h = bh & 7;
  int sbase = blockIdx.x * 64;
  int lane = threadIdx.x & 63, w = threadIdx.x >> 6;
  int lr = lane & 15, g = lane >> 4, lk = g * 8;

  const u16* Ap = Xb + ((size_t)b * SS + sbase + w * 16 + lr) * NN + lk;
  const u16* Bp = Mt + (size_t)h * NN * NN;

  bf16x8 afr[8];
  #pragma unroll
  for (int ks = 0; ks < 8; ks++) afr[ks] = *(const bf16x8*)(Ap + 32 * ks);

  f32x4 acc[16];
  #pragma unroll
  for (int n = 0; n < 16; n++) acc[n] = fzero();

  for (int n = 0; n < 16; n++){
    const u16* bp = Bp + (size_t)(n * 16 + lr) * NN + lk;
    #pragma unroll
    for (int ks = 0; ks < 8; ks++)
      acc[n] = MFMA16(afr[ks], *(const bf16x8*)(bp + 32 * ks), acc[n]);
  }
  u16* Op = Qb + ((size_t)bh * SS + sbase + w * 16) * NN;
  #pragma unroll
  for (int n = 0; n < 16; n++)
    #pragma unroll
    for (int r = 0; r < 4; r++)
      Op[(size_t)(g * 4 + r) * NN + n * 16 + lr] = f2bf(acc[n][r] * QSCALE);
}

// ---------------- V^T: Vt[b,h][q][t] = (Xb @ Wv_h)^T bf16 ----------------
__global__ __launch_bounds__(256) void vt_kernel(const u16* __restrict__ Xb,
                                                 const u16* __restrict__ Wvt,
                                                 u16* __restrict__ Vt){
  int bh = blockIdx.y, b = bh >> 3, h = bh & 7;
  int tbase = blockIdx.x * 256;
  int lane = threadIdx.x & 63, w = threadIdx.x >> 6;
  int lr = lane & 15, g = lane >> 4, lk = g * 8;

  const u16* Ap = Wvt + ((size_t)h * QQ + w * 16 + lr) * NN + lk;
  bf16x8 afr[8];
  #pragma unroll
  for (int ks = 0; ks < 8; ks++) afr[ks] = *(const bf16x8*)(Ap + 32 * ks);

  f32x4 acc[16];
  #pragma unroll
  for (int n = 0; n < 16; n++) acc[n] = fzero();

  for (int n = 0; n < 16; n++){
    const u16* bp = Xb + ((size_t)b * SS + tbase + n * 16 + lr) * NN + lk;
    #pragma unroll
    for (int ks = 0; ks < 8; ks++)
      acc[n] = MFMA16(afr[ks], *(const bf16x8*)(bp + 32 * ks), acc[n]);
  }
  u16* Op = Vt + ((size_t)bh * QQ + w * 16 + g * 4) * SS + tbase;
  #pragma unroll
  for (int n = 0; n < 16; n++)
    #pragma unroll
    for (int r = 0; r < 4; r++)
      Op[(size_t)r * SS + n * 16 + lr] = f2bf(acc[n][r]);
}

// ---------------- fused flash attention, 32x32 swapped-QK^T, double-buffered ----------
// 4 waves x 32 q-rows = 128 q/block. grid 512 (2 blocks/CU), LDS 80KB dbuf.
// Pipeline per tile: [stage kt+1 -> buf^1] [vmcnt(10)] [s_barrier] [QK|SM|PV from buf]
// [s_barrier]. Counted vmcnt keeps next tile's 10 loads in flight across compute (T4).
// NOTE: cross-half scalar reduces use __shfl_xor, NOT permlane32_swap on two copies of
// the same value — identical-value "+v" operands can coalesce to one VGPR -> self-swap
// (round-3 bug: l became 2x partner-half sum, absmax 1.3e-2).
__global__ __launch_bounds__(256, 2) void attn_kernel(const u16* __restrict__ Qb,
                                                      const u16* __restrict__ Kb,
                                                      const u16* __restrict__ Vt,
                                                      u16* __restrict__ Zc){
  int lid = blockIdx.x;
  int bh = (lid & 7) | (((lid >> 3) & 1) << 3);   // XCD-grouped by bh
  int qi = lid >> 4;
  int b = bh >> 3, h = bh & 7;

  int tid = threadIdx.x, lane = tid & 63, w = tid >> 6;
  int l31 = lane & 31, hi = lane >> 5;
  int hi16 = hi * 16;
  int sw = (lane & 7) << 4;                        // XOR bank swizzle (row&7 == lane&7)

  __shared__ u16 k_lds[2 * 64 * 256];              // 64 KB: 2 x [key][n] swizzled
  __shared__ u16 v_lds[2 * 64 * 64];               // 16 KB: 2 x [vq][key] swizzled
  char* kl = (char*)k_lds;
  char* vl = (char*)v_lds;

  // Q fragments register-resident (B-operand of swapped QK^T)
  const u16* Qp = Qb + ((size_t)bh * SS + qi * 128 + w * 32 + l31) * NN + hi * 8;
  bf16x8 qfr[16];
  #pragma unroll
  for (int ks = 0; ks < 16; ks++) qfr[ks] = *(const bf16x8*)(Qp + ks * 16);

  f32x16 o0 = zero16(), o1 = zero16();
  float m = -1e30f, l = 0.f;

  const char* Kg = (const char*)(Kb + (size_t)b * SS * NN);
  const char* Vg = (const char*)(Vt + (size_t)bh * QQ * SS);

  // staging source offsets (inverse-swizzled global so linear DMA lands swizzled)
  int koffK[8], koffV[2];
  #pragma unroll
  for (int c = 0; c < 8; c++){
    int x = c * 4096 + w * 1024 + lane * 16;
    koffK[c] = x ^ (((x >> 9) & 7) << 4);
  }
  #pragma unroll
  for (int c = 0; c < 2; c++){
    int x = c * 4096 + w * 1024 + lane * 16;       // < 8192
    int vq = x >> 7, ko = x & 127;
    koffV[c] = vq * 8192 + (ko ^ ((vq & 7) << 4));
  }
  // ds_read offsets (loop-invariant VGPRs; buffer/tile selected by imm offset)
  int kOff[16], vOff[4];
  #pragma unroll
  for (int ks = 0; ks < 16; ks++) kOff[ks] = l31 * 512 + ((ks * 32 + hi16) ^ sw);
  #pragma unroll
  for (int c = 0; c < 4; c++) vOff[c] = l31 * 128 + ((c * 32 + hi16) ^ sw);

#define STAGE(kt_, CUR_) do {                                              \
    const char* kg_ = Kg + (size_t)(kt_) * 32768;                          \
    const char* vg_ = Vg + (size_t)(kt_) * 128;                            \
    _Pragma("unroll")                                                      \
    for (int c = 0; c < 8; c++)                                            \
      gload16(kg_ + koffK[c], kl + (CUR_) * 32768 + c * 4096 + w * 1024);  \
    _Pragma("unroll")                                                      \
    for (int c = 0; c < 2; c++)                                            \
      gload16(vg_ + koffV[c], vl + (CUR_) * 8192 + c * 4096 + w * 1024);   \
  } while (0)

#define PVSTEP(P, RB, VOFF, VCONST) do {                                   \
    unsigned a_ = pkbf(P[RB+0], P[RB+1]);                                  \
    unsigned b_ = pkbf(P[RB+2], P[RB+3]);                                  \
    unsigned c_ = pkbf(P[RB+4], P[RB+5]);                                  \
    unsigned d_ = pkbf(P[RB+6], P[RB+7]);                                  \
    asm("v_permlane32_swap_b32 %0, %1" : "+v"(a_), "+v"(c_));              \
    asm("v_permlane32_swap_b32 %0, %1" : "+v"(b_), "+v"(d_));              \
    union { bf16x8 v; unsigned u[4]; } pu_;                                \
    pu_.u[0] = a_; pu_.u[1] = b_; pu_.u[2] = c_; pu_.u[3] = d_;            \
    bf16x8 vf0_ = *(const bf16x8*)(vl + (VOFF) + (VCONST));                \
    bf16x8 vf1_ = *(const bf16x8*)(vl + (VOFF) + (VCONST) + 4096);         \
    o0 = MFMA32(pu_.v, vf0_, o0);                                          \
    o1 = MFMA32(pu_.v, vf1_, o1);                                          \
  } while (0)

#define ITER(kt_, CUR_, LAST_) do {                                        \
    if (!(LAST_)) STAGE((kt_) + 1, (CUR_) ^ 1);                            \
    if (LAST_) { asm volatile("s_waitcnt vmcnt(0)" ::: "memory"); }        \
    else       { asm volatile("s_waitcnt vmcnt(10)" ::: "memory"); }       \
    __builtin_amdgcn_sched_barrier(0);                                     \
    __builtin_amdgcn_s_barrier();                                          \
    __builtin_amdgcn_sched_barrier(0);                                     \
    f32x16 p0 = zero16(), p1 = zero16();                                   \
    __builtin_amdgcn_s_setprio(1);                                         \
    _Pragma("unroll")                                                      \
    for (int ks = 0; ks < 16; ks++){                                       \
      bf16x8 k0 = *(const bf16x8*)(kl + (CUR_) * 32768 + kOff[ks]);        \
      bf16x8 k1 = *(const bf16x8*)(kl + (CUR_) * 32768 + kOff[ks] + 16384);\
      p0 = MFMA32(k0, qfr[ks], p0);                                        \
      p1 = MFMA32(k1, qfr[ks], p1);                                        \
    }                                                                      \
    __builtin_amdgcn_s_setprio(0);                                         \
    /* row max: in-register tree + cross-half shfl (NOT self-permlane) */  \
    float r_[16];                                                          \
    _Pragma("unroll")                                                      \
    for (int i = 0; i < 16; i++) r_[i] = fmaxf(p0[i], p1[i]);              \
    _Pragma("unroll")                                                      \
    for (int i = 0; i < 8; i++) r_[i] = fmaxf(r_[i], r_[i + 8]);           \
    _Pragma("unroll")                                                      \
    for (int i = 0; i < 4; i++) r_[i] = fmaxf(r_[i], r_[i + 4]);           \
    float pm = fmaxf(fmaxf(r_[0], r_[1]), fmaxf(r_[2], r_[3]));            \
    pm = fmaxf(pm, __shfl_xor(pm, 32));                                    \
    if (__any(pm > m + 8.0f)){                 /* defer-max (T13) */       \
      float mn_ = fmaxf(m, pm);                                            \
      float fs_ = exp2f(m - mn_);                                          \
      m = mn_; l *= fs_;                                                   \
      _Pragma("unroll")                                                    \
      for (int i = 0; i < 16; i++){                                        \
        int q_ = (i & 3) + 8 * (i >> 2) + 4 * hi;                          \
        float fv_ = __int_as_float(__builtin_amdgcn_ds_bpermute(           \
                        q_ << 2, __float_as_int(fs_)));                    \
        o0[i] *= fv_; o1[i] *= fv_;                                        \
      }                                                                    \
    }                                                                      \
    _Pragma("unroll")                                                      \
    for (int i = 0; i < 16; i++){                                          \
      p0[i] = exp2f(p0[i] - m);                                            \
      p1[i] = exp2f(p1[i] - m);                                            \
    }                                                                      \
    { float s_[16];                                                        \
      _Pragma("unroll")                                                    \
      for (int i = 0; i < 16; i++) s_[i] = p0[i] + p1[i];                  \
      _Pragma("unroll")                                                    \
      for (int i = 0; i < 8; i++) s_[i] += s_[i + 8];                      \
      _Pragma("unroll")                                                    \
      for (int i = 0; i < 4; i++) s_[i] += s_[i + 4];                      \
      float ps_ = (s_[0] + s_[1]) + (s_[2] + s_[3]);                       \
      ps_ += __shfl_xor(ps_, 32);                                          \
      l += ps_; }                                                          \
    __builtin_amdgcn_s_setprio(1);                                         \
    PVSTEP(p0, 0, vOff[0], (CUR_) * 8192);                                 \
    PVSTEP(p0, 8, vOff[1], (CUR_) * 8192);                                 \
    PVSTEP(p1, 0, vOff[2], (CUR_) * 8192);                                 \
    PVSTEP(p1, 8, vOff[3], (CUR_) * 8192);                                 \
    __builtin_amdgcn_s_setprio(0);                                         \
    __builtin_amdgcn_s_barrier();                                          \
    __builtin_amdgcn_sched_barrier(0);                                     \
  } while (0)

  STAGE(0, 0);
  for (int kt2 = 0; kt2 < 31; kt2++){
    ITER(2 * kt2,     0, 0);
    ITER(2 * kt2 + 1, 1, 0);
  }
  ITER(62, 0, 0);
  ITER(63, 1, 1);
#undef ITER
#undef PVSTEP
#undef STAGE

  // epilogue: normalize by 1/l (broadcast via ds_bpermute), write Zc bf16
  float inv = 1.0f / l;
  u16* Op = Zc + ((size_t)b * SS + qi * 128 + w * 32) * (HH * QQ) + h * QQ;
  #pragma unroll
  for (int i = 0; i < 16; i++){
    int q = (i & 3) + 8 * (i >> 2) + 4 * hi;
    float fv = __int_as_float(__builtin_amdgcn_ds_bpermute(q << 2, __float_as_int(inv)));
    u16* row = Op + (size_t)q * (HH * QQ);
    row[l31]      = f2bf(o0[i] * fv);
    row[32 + l31] = f2bf(o1[i] * fv);
  }
}

// ---------------- out = Zc @ W0 (fp32 out) ----------------
__global__ __launch_bounds__(256) void out_kernel(const u16* __restrict__ Zc,
                                                  const u16* __restrict__ W0t,
                                                  float* __restrict__ out){
  int rbase = blockIdx.x * 64, cbase = blockIdx.y * 128;
  int lane = threadIdx.x & 63, w = threadIdx.x >> 6;
  int lr = lane & 15, g = lane >> 4, lk = g * 8;

  const u16* Ap = Zc + (size_t)(rbase + w * 16 + lr) * ZZ + lk;
  f32x4 acc[8];
  #pragma unroll
  for (int n = 0; n < 8; n++) acc[n] = fzero();

  for (int ks = 0; ks < 16; ks++){
    bf16x8 afr = *(const bf16x8*)(Ap + 32 * ks);
    #pragma unroll
    for (int n = 0; n < 8; n++){
      const u16* bp = W0t + (size_t)(cbase + n * 16 + lr) * ZZ + lk + 32 * ks;
      acc[n] = MFMA16(afr, *(const bf16x8*)bp, acc[n]);
    }
  }
  float* Op = out + (size_t)(rbase + w * 16 + g * 4) * ZZ + cbase;
  #pragma unroll
  for (int n = 0; n < 8; n++)
    #pragma unroll
    for (int r = 0; r < 4; r++)
      Op[(size_t)r * ZZ + n * 16 + lr] = acc[n][r];
}

extern "C" void kernel_launch(void* const* d_in, const int* in_sizes, int n_in,
                              void* d_out, int out_size, void* d_ws, size_t ws_size,
                              hipStream_t stream){
  (void)in_sizes; (void)n_in; (void)out_size; (void)ws_size;
  const float* X  = (const float*)d_in[0];   // [B,S,N]
  const float* M  = (const float*)d_in[1];   // [H,N,N]
  const float* Wv = (const float*)d_in[2];   // [H,N,Q]
  const float* W0 = (const float*)d_in[3];   // [H*Q,Z]
  float* out = (float*)d_out;                // [B,S,Z] fp32

  char* ws = (char*)d_ws;
  size_t off = 0;
  auto alloc = [&](size_t bytes) -> void* {
    void* p = ws + off; off += (bytes + 255) & ~(size_t)255; return p;
  };
  u16* Kb  = (u16*)alloc((size_t)BB * SS * NN * 2);        // X as bf16
  u16* Qb  = (u16*)alloc((size_t)BB * HH * SS * NN * 2);   // (X@M_h) scaled bf16
  u16* Vtb = (u16*)alloc((size_t)BB * HH * QQ * SS * 2);   // V transposed bf16
  u16* Mt  = (u16*)alloc((size_t)HH * NN * NN * 2);
  u16* Wvt = (u16*)alloc((size_t)HH * QQ * NN * 2);
  u16* W0t = (u16*)alloc((size_t)ZZ * ZZ * 2);
  u16* Zc  = (u16*)alloc((size_t)BB * SS * HH * QQ * 2);

  cast_x_kernel<<<dim3(BB * SS * NN / 1024), dim3(256), 0, stream>>>(X, Kb);
  transpose_cast_kernel<<<dim3(NN/32, NN/32, HH), dim3(256), 0, stream>>>(M,  Mt,  NN, NN);
  transpose_cast_kernel<<<dim3(QQ/32, NN/32, HH), dim3(256), 0, stream>>>(Wv, Wvt, NN, QQ);
  transpose_cast_kernel<<<dim3(ZZ/32, ZZ/32, 1),  dim3(256), 0, stream>>>(W0, W0t, ZZ, ZZ);
  xm_kernel<<<dim3(SS/64, BB*HH),  dim3(256), 0, stream>>>(Kb, Mt, Qb);
  vt_kernel<<<dim3(SS/256, BB*HH), dim3(256), 0, stream>>>(Kb, Wvt, Vtb);
  attn_kernel<<<dim3(512), dim3(256), 0, stream>>>(Qb, Kb, Vtb, Zc);
  out_kernel<<<dim3(BB*SS/64, ZZ/128), dim3(256), 0, stream>>>(Zc, W0t, out);
}

// Round 5
// 360.669 us; speedup vs baseline: 1.6497x; 1.1053x over previous
//
#include <hip/hip_runtime.h>

typedef unsigned short u16;
typedef unsigned long long uptr;
typedef __attribute__((ext_vector_type(8))) short bf16x8;   // 8 bf16 = 4 VGPRs
typedef __attribute__((ext_vector_type(4))) float f32x4;
typedef __attribute__((ext_vector_type(16))) float f32x16;

#define MFMA16(a,b,c) __builtin_amdgcn_mfma_f32_16x16x32_bf16((a),(b),(c),0,0,0)
#define MFMA32(a,b,c) __builtin_amdgcn_mfma_f32_32x32x16_bf16((a),(b),(c),0,0,0)

// Problem dims
#define BB 2
#define SS 4096
#define NN 256
#define HH 8
#define QQ 64
#define ZZ 512

__device__ __forceinline__ u16 f2bf(float f){           // RNE fp32->bf16 (finite data)
  unsigned int u = __float_as_uint(f);
  u += 0x7fffu + ((u >> 16) & 1u);
  return (u16)(u >> 16);
}

__device__ __forceinline__ f32x4 fzero(){ f32x4 z = {0.f,0.f,0.f,0.f}; return z; }

__device__ __forceinline__ f32x16 zero16(){
  f32x16 z;
  #pragma unroll
  for (int i = 0; i < 16; i++) z[i] = 0.f;
  return z;
}

__device__ __forceinline__ unsigned pkbf(float a, float b){  // low16=bf16(a), high16=bf16(b)
  unsigned r;
  asm("v_cvt_pk_bf16_f32 %0, %1, %2" : "=v"(r) : "v"(a), "v"(b));
  return r;
}

// async global->LDS, 16B per lane (dest = wave-uniform base + lane*16; src per-lane)
typedef __attribute__((address_space(1))) const void gas_void;
typedef __attribute__((address_space(3))) void las_void;
__device__ __forceinline__ void gload16(const void* g, void* l){
  __builtin_amdgcn_global_load_lds((gas_void*)(uptr)g,
                                   (las_void*)(uptr)(unsigned)(uptr)l, 16, 0, 0);
}

// ---------------- fused prep: cast X -> bf16; transpose+cast M, Wv, W0 ----------------
__device__ __forceinline__ void do_transpose(const float* __restrict__ ip,
                                             u16* __restrict__ op, int R, int C,
                                             int bx, int by, float (*t)[33], int tid){
  int c0 = bx * 32, r0 = by * 32;
  int c = tid & 31, r = tid >> 5;                      // 32 x 8
  #pragma unroll
  for (int rr = 0; rr < 32; rr += 8)
    t[r + rr][c] = ip[(size_t)(r0 + r + rr) * C + (c0 + c)];
  __syncthreads();
  #pragma unroll
  for (int rr = 0; rr < 32; rr += 8)
    op[(size_t)(c0 + r + rr) * R + (r0 + c)] = f2bf(t[c][r + rr]);
}

// grid: [0,2048) cast X | [2048,2560) M 8x8x8 | [2560,2688) Wv 2x8x8 | [2688,2944) W0 16x16
__global__ __launch_bounds__(256) void prep_kernel(const float* __restrict__ X,
                                                   const float* __restrict__ M,
                                                   const float* __restrict__ Wv,
                                                   const float* __restrict__ W0,
                                                   u16* __restrict__ Kb,
                                                   u16* __restrict__ Mt,
                                                   u16* __restrict__ Wvt,
                                                   u16* __restrict__ W0t){
  __shared__ float t[32][33];
  int bid = blockIdx.x, tid = threadIdx.x;
  if (bid < 2048){
    int i = bid * 256 + tid;
    float4 v = ((const float4*)X)[i];
    ushort4 o;
    o.x = f2bf(v.x); o.y = f2bf(v.y); o.z = f2bf(v.z); o.w = f2bf(v.w);
    ((ushort4*)Kb)[i] = o;
    return;
  }
  int b2 = bid - 2048;
  if (b2 < 512){
    int bz = b2 >> 6, by = (b2 >> 3) & 7, bx = b2 & 7;
    do_transpose(M + (size_t)bz * NN * NN, Mt + (size_t)bz * NN * NN, NN, NN, bx, by, t, tid);
  } else if (b2 < 640){
    int b3 = b2 - 512;
    int bz = b3 >> 4, by = (b3 >> 1) & 7, bx = b3 & 1;
    do_transpose(Wv + (size_t)bz * NN * QQ, Wvt + (size_t)bz * NN * QQ, NN, QQ, bx, by, t, tid);
  } else {
    int b4 = b2 - 640;
    int by = b4 >> 4, bx = b4 & 15;
    do_transpose(W0, W0t, ZZ, ZZ, bx, by, t, tid);
  }
}

// ---------------- V^T: Vt[b,h][q][t] = (Xb @ Wv_h)^T bf16 ----------------
__global__ __launch_bounds__(256) void vt_kernel(const u16* __restrict__ Xb,
                                                 const u16* __restrict__ Wvt,
                                                 u16* __restrict__ Vt){
  int bh = blockIdx.y, b = bh >> 3, h = bh & 7;
  int tbase = blockIdx.x * 256;
  int lane = threadIdx.x & 63, w = threadIdx.x >> 6;
  int lr = lane & 15, g = lane >> 4, lk = g * 8;

  const u16* Ap = Wvt + ((size_t)h * QQ + w * 16 + lr) * NN + lk;
  bf16x8 afr[8];
  #pragma unroll
  for (int ks = 0; ks < 8; ks++) afr[ks] = *(const bf16x8*)(Ap + 32 * ks);

  f32x4 acc[16];
  #pragma unroll
  for (int n = 0; n < 16; n++) acc[n] = fzero();

  for (int n = 0; n < 16; n++){
    const u16* bp = Xb + ((size_t)b * SS + tbase + n * 16 + lr) * NN + lk;
    #pragma unroll
    for (int ks = 0; ks < 8; ks++)
      acc[n] = MFMA16(afr[ks], *(const bf16x8*)(bp + 32 * ks), acc[n]);
  }
  u16* Op = Vt + ((size_t)bh * QQ + w * 16 + g * 4) * SS + tbase;
  #pragma unroll
  for (int n = 0; n < 16; n++)
    #pragma unroll
    for (int r = 0; r < 4; r++)
      Op[(size_t)r * SS + n * 16 + lr] = f2bf(acc[n][r]);
}

// ---------------- fused XM + flash attention, 32x32 swapped-QK^T, double-buffered -----
// 4 waves x 32 q-rows = 128 q/block. grid 512 (2 blocks/CU), LDS 80KB dbuf.
// Prologue: each wave computes its own Q rows = (X @ M_h)*QSCALE on the matrix pipe
// (128 MFMA32 from L2-hot Mt), packing acc->qfr via cvt_pk + permlane32_swap — the
// same reg->k-slot mapping as PVSTEP (verified). Kills the xm kernel + Qb round-trip.
// Loop: [stage kt+1 -> buf^1] [vmcnt(10)] [s_barrier] [QK|SM|PV from buf] [s_barrier].
// NOTE: cross-half scalar reduces use __shfl_xor, NOT permlane32_swap on two copies of
// one value (identical "+v" operands can coalesce -> self-swap; round-3 bug).
__global__ __launch_bounds__(256, 2) void attn_kernel(const u16* __restrict__ Mt,
                                                      const u16* __restrict__ Kb,
                                                      const u16* __restrict__ Vt,
                                                      u16* __restrict__ Zc){
  int lid = blockIdx.x;
  int bh = (lid & 7) | (((lid >> 3) & 1) << 3);   // XCD-grouped by bh
  int qi = lid >> 4;
  int b = bh >> 3, h = bh & 7;

  int tid = threadIdx.x, lane = tid & 63, w = tid >> 6;
  int l31 = lane & 31, hi = lane >> 5;
  int hi16 = hi * 16;
  int sw = (lane & 7) << 4;                        // XOR bank swizzle (row&7 == lane&7)

  __shared__ u16 k_lds[2 * 64 * 256];              // 64 KB: 2 x [key][n] swizzled
  __shared__ u16 v_lds[2 * 64 * 64];               // 16 KB: 2 x [vq][key] swizzled
  char* kl = (char*)k_lds;
  char* vl = (char*)v_lds;

  int qrow = qi * 128 + w * 32 + l31;

  const char* Kg = (const char*)(Kb + (size_t)b * SS * NN);
  const char* Vg = (const char*)(Vt + (size_t)bh * QQ * SS);

  // staging source offsets (inverse-swizzled global so linear DMA lands swizzled)
  int koffK[8], koffV[2];
  #pragma unroll
  for (int c = 0; c < 8; c++){
    int x = c * 4096 + w * 1024 + lane * 16;
    koffK[c] = x ^ (((x >> 9) & 7) << 4);
  }
  #pragma unroll
  for (int c = 0; c < 2; c++){
    int x = c * 4096 + w * 1024 + lane * 16;       // < 8192
    int vq = x >> 7, ko = x & 127;
    koffV[c] = vq * 8192 + (ko ^ ((vq & 7) << 4));
  }
  // ds_read offsets (loop-invariant VGPRs; buffer/tile selected by imm offset)
  int kOff[16], vOff[4];
  #pragma unroll
  for (int ks = 0; ks < 16; ks++) kOff[ks] = l31 * 512 + ((ks * 32 + hi16) ^ sw);
  #pragma unroll
  for (int c = 0; c < 4; c++) vOff[c] = l31 * 128 + ((c * 32 + hi16) ^ sw);

#define STAGE(kt_, CUR_) do {                                              \
    const char* kg_ = Kg + (size_t)(kt_) * 32768;                          \
    const char* vg_ = Vg + (size_t)(kt_) * 128;                            \
    _Pragma("unroll")                                                      \
    for (int c = 0; c < 8; c++)                                            \
      gload16(kg_ + koffK[c], kl + (CUR_) * 32768 + c * 4096 + w * 1024);  \
    _Pragma("unroll")                                                      \
    for (int c = 0; c < 2; c++)                                            \
      gload16(vg_ + koffV[c], vl + (CUR_) * 8192 + c * 4096 + w * 1024);   \
  } while (0)

  // kick off tile 0 DMA first; XM prologue compute hides its latency
  STAGE(0, 0);

  // --- fused XM prologue: qfr[ks][j] = bf16(Q[qrow][ks*16 + hi*8 + j] * QSCALE) ---
  bf16x8 qfr[16];
  {
    const float QSCALE = 0.015625f * 1.4426950408889634f;  // 1/64 * log2(e)
    const u16* Xp = Kb + ((size_t)b * SS + qrow) * NN + hi * 8;
    bf16x8 xfr[16];
    #pragma unroll
    for (int kk = 0; kk < 16; kk++) xfr[kk] = *(const bf16x8*)(Xp + kk * 16);
    const u16* Mh = Mt + (size_t)h * NN * NN;
    #pragma unroll
    for (int ct = 0; ct < 8; ct++){
      f32x16 acc = zero16();
      const u16* ap = Mh + (size_t)(ct * 32 + l31) * NN + hi * 8;
      #pragma unroll
      for (int kk = 0; kk < 16; kk++)
        acc = MFMA32(*(const bf16x8*)(ap + kk * 16), xfr[kk], acc);
      #pragma unroll
      for (int i = 0; i < 16; i++) acc[i] *= QSCALE;
      {
        unsigned a0 = pkbf(acc[0], acc[1]),  b0 = pkbf(acc[2], acc[3]);
        unsigned c0 = pkbf(acc[4], acc[5]),  d0 = pkbf(acc[6], acc[7]);
        asm("v_permlane32_swap_b32 %0, %1" : "+v"(a0), "+v"(c0));
        asm("v_permlane32_swap_b32 %0, %1" : "+v"(b0), "+v"(d0));
        union { bf16x8 v; unsigned u[4]; } u0;
        u0.u[0] = a0; u0.u[1] = b0; u0.u[2] = c0; u0.u[3] = d0;
        qfr[2 * ct] = u0.v;
      }
      {
        unsigned a1 = pkbf(acc[8], acc[9]),   b1 = pkbf(acc[10], acc[11]);
        unsigned c1 = pkbf(acc[12], acc[13]), d1 = pkbf(acc[14], acc[15]);
        asm("v_permlane32_swap_b32 %0, %1" : "+v"(a1), "+v"(c1));
        asm("v_permlane32_swap_b32 %0, %1" : "+v"(b1), "+v"(d1));
        union { bf16x8 v; unsigned u[4]; } u1;
        u1.u[0] = a1; u1.u[1] = b1; u1.u[2] = c1; u1.u[3] = d1;
        qfr[2 * ct + 1] = u1.v;
      }
    }
  }

  f32x16 o0 = zero16(), o1 = zero16();
  float m = -1e30f, l = 0.f;

#define PVSTEP(P, RB, VOFF, VCONST) do {                                   \
    unsigned a_ = pkbf(P[RB+0], P[RB+1]);                                  \
    unsigned b_ = pkbf(P[RB+2], P[RB+3]);                                  \
    unsigned c_ = pkbf(P[RB+4], P[RB+5]);                                  \
    unsigned d_ = pkbf(P[RB+6], P[RB+7]);                                  \
    asm("v_permlane32_swap_b32 %0, %1" : "+v"(a_), "+v"(c_));              \
    asm("v_permlane32_swap_b32 %0, %1" : "+v"(b_), "+v"(d_));              \
    union { bf16x8 v; unsigned u[4]; } pu_;                                \
    pu_.u[0] = a_; pu_.u[1] = b_; pu_.u[2] = c_; pu_.u[3] = d_;            \
    bf16x8 vf0_ = *(const bf16x8*)(vl + (VOFF) + (VCONST));                \
    bf16x8 vf1_ = *(const bf16x8*)(vl + (VOFF) + (VCONST) + 4096);         \
    o0 = MFMA32(pu_.v, vf0_, o0);                                          \
    o1 = MFMA32(pu_.v, vf1_, o1);                                          \
  } while (0)

#define ITER(kt_, CUR_, LAST_) do {                                        \
    if (!(LAST_)) STAGE((kt_) + 1, (CUR_) ^ 1);                            \
    if (LAST_) { asm volatile("s_waitcnt vmcnt(0)" ::: "memory"); }        \
    else       { asm volatile("s_waitcnt vmcnt(10)" ::: "memory"); }       \
    __builtin_amdgcn_sched_barrier(0);                                     \
    __builtin_amdgcn_s_barrier();                                          \
    __builtin_amdgcn_sched_barrier(0);                                     \
    f32x16 p0 = zero16(), p1 = zero16();                                   \
    __builtin_amdgcn_s_setprio(1);                                         \
    _Pragma("unroll")                                                      \
    for (int ks = 0; ks < 16; ks++){                                       \
      bf16x8 k0 = *(const bf16x8*)(kl + (CUR_) * 32768 + kOff[ks]);        \
      bf16x8 k1 = *(const bf16x8*)(kl + (CUR_) * 32768 + kOff[ks] + 16384);\
      p0 = MFMA32(k0, qfr[ks], p0);                                        \
      p1 = MFMA32(k1, qfr[ks], p1);                                        \
    }                                                                      \
    __builtin_amdgcn_s_setprio(0);                                         \
    /* row max: in-register tree + cross-half shfl (NOT self-permlane) */  \
    float r_[16];                                                          \
    _Pragma("unroll")                                                      \
    for (int i = 0; i < 16; i++) r_[i] = fmaxf(p0[i], p1[i]);              \
    _Pragma("unroll")                                                      \
    for (int i = 0; i < 8; i++) r_[i] = fmaxf(r_[i], r_[i + 8]);           \
    _Pragma("unroll")                                                      \
    for (int i = 0; i < 4; i++) r_[i] = fmaxf(r_[i], r_[i + 4]);           \
    float pm = fmaxf(fmaxf(r_[0], r_[1]), fmaxf(r_[2], r_[3]));            \
    pm = fmaxf(pm, __shfl_xor(pm, 32));                                    \
    if (__any(pm > m + 8.0f)){                 /* defer-max (T13) */       \
      float mn_ = fmaxf(m, pm);                                            \
      float fs_ = exp2f(m - mn_);                                          \
      m = mn_; l *= fs_;                                                   \
      _Pragma("unroll")                                                    \
      for (int i = 0; i < 16; i++){                                        \
        int q_ = (i & 3) + 8 * (i >> 2) + 4 * hi;                          \
        float fv_ = __int_as_float(__builtin_amdgcn_ds_bpermute(           \
                        q_ << 2, __float_as_int(fs_)));                    \
        o0[i] *= fv_; o1[i] *= fv_;                                        \
      }                                                                    \
    }                                                                      \
    _Pragma("unroll")                                                      \
    for (int i = 0; i < 16; i++){                                          \
      p0[i] = exp2f(p0[i] - m);                                            \
      p1[i] = exp2f(p1[i] - m);                                            \
    }                                                                      \
    { float s_[16];                                                        \
      _Pragma("unroll")                                                    \
      for (int i = 0; i < 16; i++) s_[i] = p0[i] + p1[i];                  \
      _Pragma("unroll")                                                    \
      for (int i = 0; i < 8; i++) s_[i] += s_[i + 8];                      \
      _Pragma("unroll")                                                    \
      for (int i = 0; i < 4; i++) s_[i] += s_[i + 4];                      \
      float ps_ = (s_[0] + s_[1]) + (s_[2] + s_[3]);                       \
      ps_ += __shfl_xor(ps_, 32);                                          \
      l += ps_; }                                                          \
    __builtin_amdgcn_s_setprio(1);                                         \
    PVSTEP(p0, 0, vOff[0], (CUR_) * 8192);                                 \
    PVSTEP(p0, 8, vOff[1], (CUR_) * 8192);                                 \
    PVSTEP(p1, 0, vOff[2], (CUR_) * 8192);                                 \
    PVSTEP(p1, 8, vOff[3], (CUR_) * 8192);                                 \
    __builtin_amdgcn_s_setprio(0);                                         \
    __builtin_amdgcn_s_barrier();                                          \
    __builtin_amdgcn_sched_barrier(0);                                     \
  } while (0)

  for (int kt2 = 0; kt2 < 31; kt2++){
    ITER(2 * kt2,     0, 0);
    ITER(2 * kt2 + 1, 1, 0);
  }
  ITER(62, 0, 0);
  ITER(63, 1, 1);
#undef ITER
#undef PVSTEP
#undef STAGE

  // epilogue: normalize by 1/l (broadcast via ds_bpermute), write Zc bf16
  float inv = 1.0f / l;
  u16* Op = Zc + ((size_t)b * SS + qi * 128 + w * 32) * (HH * QQ) + h * QQ;
  #pragma unroll
  for (int i = 0; i < 16; i++){
    int q = (i & 3) + 8 * (i >> 2) + 4 * hi;
    float fv = __int_as_float(__builtin_amdgcn_ds_bpermute(q << 2, __float_as_int(inv)));
    u16* row = Op + (size_t)q * (HH * QQ);
    row[l31]      = f2bf(o0[i] * fv);
    row[32 + l31] = f2bf(o1[i] * fv);
  }
}

// ---------------- out = Zc @ W0 (fp32 out) ----------------
__global__ __launch_bounds__(256) void out_kernel(const u16* __restrict__ Zc,
                                                  const u16* __restrict__ W0t,
                                                  float* __restrict__ out){
  int rbase = blockIdx.x * 64, cbase = blockIdx.y * 128;
  int lane = threadIdx.x & 63, w = threadIdx.x >> 6;
  int lr = lane & 15, g = lane >> 4, lk = g * 8;

  const u16* Ap = Zc + (size_t)(rbase + w * 16 + lr) * ZZ + lk;
  f32x4 acc[8];
  #pragma unroll
  for (int n = 0; n < 8; n++) acc[n] = fzero();

  for (int ks = 0; ks < 16; ks++){
    bf16x8 afr = *(const bf16x8*)(Ap + 32 * ks);
    #pragma unroll
    for (int n = 0; n < 8; n++){
      const u16* bp = W0t + (size_t)(cbase + n * 16 + lr) * ZZ + lk + 32 * ks;
      acc[n] = MFMA16(afr, *(const bf16x8*)bp, acc[n]);
    }
  }
  float* Op = out + (size_t)(rbase + w * 16 + g * 4) * ZZ + cbase;
  #pragma unroll
  for (int n = 0; n < 8; n++)
    #pragma unroll
    for (int r = 0; r < 4; r++)
      Op[(size_t)r * ZZ + n * 16 + lr] = acc[n][r];
}

extern "C" void kernel_launch(void* const* d_in, const int* in_sizes, int n_in,
                              void* d_out, int out_size, void* d_ws, size_t ws_size,
                              hipStream_t stream){
  (void)in_sizes; (void)n_in; (void)out_size; (void)ws_size;
  const float* X  = (const float*)d_in[0];   // [B,S,N]
  const float* M  = (const float*)d_in[1];   // [H,N,N]
  const float* Wv = (const float*)d_in[2];   // [H,N,Q]
  const float* W0 = (const float*)d_in[3];   // [H*Q,Z]
  float* out = (float*)d_out;                // [B,S,Z] fp32

  char* ws = (char*)d_ws;
  size_t off = 0;
  auto alloc = [&](size_t bytes) -> void* {
    void* p = ws + off; off += (bytes + 255) & ~(size_t)255; return p;
  };
  u16* Kb  = (u16*)alloc((size_t)BB * SS * NN * 2);        // X as bf16
  u16* Vtb = (u16*)alloc((size_t)BB * HH * QQ * SS * 2);   // V transposed bf16
  u16* Mt  = (u16*)alloc((size_t)HH * NN * NN * 2);
  u16* Wvt = (u16*)alloc((size_t)HH * QQ * NN * 2);
  u16* W0t = (u16*)alloc((size_t)ZZ * ZZ * 2);
  u16* Zc  = (u16*)alloc((size_t)BB * SS * HH * QQ * 2);

  prep_kernel<<<dim3(2944), dim3(256), 0, stream>>>(X, M, Wv, W0, Kb, Mt, Wvt, W0t);
  vt_kernel<<<dim3(SS/256, BB*HH), dim3(256), 0, stream>>>(Kb, Wvt, Vtb);
  attn_kernel<<<dim3(512), dim3(256), 0, stream>>>(Mt, Kb, Vtb, Zc);
  out_kernel<<<dim3(BB*SS/64, ZZ/128), dim3(256), 0, stream>>>(Zc, W0t, out);
}

// Round 6
// 344.481 us; speedup vs baseline: 1.7273x; 1.0470x over previous
//
#include <hip/hip_runtime.h>

typedef unsigned short u16;
typedef unsigned long long uptr;
typedef __attribute__((ext_vector_type(8))) short bf16x8;   // 8 bf16 = 4 VGPRs
typedef __attribute__((ext_vector_type(4))) float f32x4;
typedef __attribute__((ext_vector_type(16))) float f32x16;

#define MFMA16(a,b,c) __builtin_amdgcn_mfma_f32_16x16x32_bf16((a),(b),(c),0,0,0)
#define MFMA32(a,b,c) __builtin_amdgcn_mfma_f32_32x32x16_bf16((a),(b),(c),0,0,0)

// Problem dims
#define BB 2
#define SS 4096
#define NN 256
#define HH 8
#define QQ 64
#define ZZ 512

__device__ __forceinline__ u16 f2bf(float f){           // RNE fp32->bf16 (finite data)
  unsigned int u = __float_as_uint(f);
  u += 0x7fffu + ((u >> 16) & 1u);
  return (u16)(u >> 16);
}

__device__ __forceinline__ f32x4 fzero(){ f32x4 z = {0.f,0.f,0.f,0.f}; return z; }

__device__ __forceinline__ f32x16 zero16(){
  f32x16 z;
  #pragma unroll
  for (int i = 0; i < 16; i++) z[i] = 0.f;
  return z;
}

__device__ __forceinline__ unsigned pkbf(float a, float b){  // low16=bf16(a), high16=bf16(b)
  unsigned r;
  asm("v_cvt_pk_bf16_f32 %0, %1, %2" : "=v"(r) : "v"(a), "v"(b));
  return r;
}

// async global->LDS, 16B per lane (dest = wave-uniform base + lane*16; src per-lane)
typedef __attribute__((address_space(1))) const void gas_void;
typedef __attribute__((address_space(3))) void las_void;
__device__ __forceinline__ void gload16(const void* g, void* l){
  __builtin_amdgcn_global_load_lds((gas_void*)(uptr)g,
                                   (las_void*)(uptr)(unsigned)(uptr)l, 16, 0, 0);
}

// ---------------- fused prep ----------------
// cast X -> bf16; M -> fragment-linear Mq; transpose+cast Wv, W0.
// Mq layout: [h][ct][kk][lane] x 8 bf16, so the attn prologue's A-frag load is
// base + lane*16B (coalesced 1KB/instr). Element (h,ct,kk,lane=hi*32+l31,j) =
// M[h][kk*16+hi*8+j][ct*32+l31]  (identical to the old Mt-row fragment).
__device__ __forceinline__ void do_transpose(const float* __restrict__ ip,
                                             u16* __restrict__ op, int R, int C,
                                             int bx, int by, float (*t)[33], int tid){
  int c0 = bx * 32, r0 = by * 32;
  int c = tid & 31, r = tid >> 5;                      // 32 x 8
  #pragma unroll
  for (int rr = 0; rr < 32; rr += 8)
    t[r + rr][c] = ip[(size_t)(r0 + r + rr) * C + (c0 + c)];
  __syncthreads();
  #pragma unroll
  for (int rr = 0; rr < 32; rr += 8)
    op[(size_t)(c0 + r + rr) * R + (r0 + c)] = f2bf(t[c][r + rr]);
}

// grid: [0,2048) cast X | [2048,2112) Mq gather | [2112,2240) Wv | [2240,2496) W0
__global__ __launch_bounds__(256) void prep_kernel(const float* __restrict__ X,
                                                   const float* __restrict__ M,
                                                   const float* __restrict__ Wv,
                                                   const float* __restrict__ W0,
                                                   u16* __restrict__ Kb,
                                                   u16* __restrict__ Mq,
                                                   u16* __restrict__ Wvt,
                                                   u16* __restrict__ W0t){
  __shared__ float t[32][33];
  int bid = blockIdx.x, tid = threadIdx.x;
  if (bid < 2048){
    int i = bid * 256 + tid;
    float4 v = ((const float4*)X)[i];
    ushort4 o;
    o.x = f2bf(v.x); o.y = f2bf(v.y); o.z = f2bf(v.z); o.w = f2bf(v.w);
    ((ushort4*)Kb)[i] = o;
    return;
  }
  int b2 = bid - 2048;
  if (b2 < 64){                                        // Mq fragment-linear gather
    int h = b2 >> 3, ct = b2 & 7;
    const float* Msrc = M + (size_t)h * NN * NN;
    u16* dst = Mq + (size_t)(h * 8 + ct) * 8192;
    #pragma unroll
    for (int rep = 0; rep < 4; rep++){
      int p = rep * 256 + tid;                         // [0,1024): (kk,lane)
      int kk = p >> 6, lane = p & 63;
      int l31 = lane & 31, hi = lane >> 5;
      const float* s = Msrc + (size_t)(kk * 16 + hi * 8) * NN + ct * 32 + l31;
      union { u16 u[8]; uint4 v; } tmp;
      #pragma unroll
      for (int j = 0; j < 8; j++) tmp.u[j] = f2bf(s[(size_t)j * NN]);
      *(uint4*)(dst + (size_t)p * 8) = tmp.v;
    }
    return;
  }
  if (b2 < 192){
    int b3 = b2 - 64;
    int bz = b3 >> 4, by = (b3 >> 1) & 7, bx = b3 & 1;
    do_transpose(Wv + (size_t)bz * NN * QQ, Wvt + (size_t)bz * NN * QQ, NN, QQ, bx, by, t, tid);
  } else {
    int b4 = b2 - 192;
    int by = b4 >> 4, bx = b4 & 15;
    do_transpose(W0, W0t, ZZ, ZZ, bx, by, t, tid);
  }
}

// ---------------- V^T: Vt[b,h][q][t] = (Xb @ Wv_h)^T bf16 ----------------
__global__ __launch_bounds__(256) void vt_kernel(const u16* __restrict__ Xb,
                                                 const u16* __restrict__ Wvt,
                                                 u16* __restrict__ Vt){
  int bh = blockIdx.y, b = bh >> 3, h = bh & 7;
  int tbase = blockIdx.x * 256;
  int lane = threadIdx.x & 63, w = threadIdx.x >> 6;
  int lr = lane & 15, g = lane >> 4, lk = g * 8;

  const u16* Ap = Wvt + ((size_t)h * QQ + w * 16 + lr) * NN + lk;
  bf16x8 afr[8];
  #pragma unroll
  for (int ks = 0; ks < 8; ks++) afr[ks] = *(const bf16x8*)(Ap + 32 * ks);

  f32x4 acc[16];
  #pragma unroll
  for (int n = 0; n < 16; n++) acc[n] = fzero();

  for (int n = 0; n < 16; n++){
    const u16* bp = Xb + ((size_t)b * SS + tbase + n * 16 + lr) * NN + lk;
    #pragma unroll
    for (int ks = 0; ks < 8; ks++)
      acc[n] = MFMA16(afr[ks], *(const bf16x8*)(bp + 32 * ks), acc[n]);
  }
  u16* Op = Vt + ((size_t)bh * QQ + w * 16 + g * 4) * SS + tbase;
  #pragma unroll
  for (int n = 0; n < 16; n++)
    #pragma unroll
    for (int r = 0; r < 4; r++)
      Op[(size_t)r * SS + n * 16 + lr] = f2bf(acc[n][r]);
}

// ---------------- fused XM + flash attention, 32x32 swapped-QK^T, double-buffered -----
// 4 waves x 32 q-rows = 128 q/block. grid 512 (2 blocks/CU), LDS 80KB dbuf.
// Prologue: Q = (X @ M_h)*QSCALE on the matrix pipe, A-frags from Mq (fragment-linear,
// coalesced base+lane*16B loads), packed acc->qfr via cvt_pk + permlane32_swap.
// Loop: [stage kt+1 -> buf^1] [vmcnt(10)] [s_barrier] [QK|SM|PV from buf] [s_barrier].
// NOTE: cross-half scalar reduces use __shfl_xor, NOT permlane32_swap on two copies of
// one value (identical "+v" operands can coalesce -> self-swap; round-3 bug).
__global__ __launch_bounds__(256, 2) void attn_kernel(const u16* __restrict__ Mq,
                                                      const u16* __restrict__ Kb,
                                                      const u16* __restrict__ Vt,
                                                      u16* __restrict__ Zc){
  int lid = blockIdx.x;
  int bh = (lid & 7) | (((lid >> 3) & 1) << 3);   // XCD-grouped by bh
  int qi = lid >> 4;
  int b = bh >> 3, h = bh & 7;

  int tid = threadIdx.x, lane = tid & 63, w = tid >> 6;
  int l31 = lane & 31, hi = lane >> 5;
  int hi16 = hi * 16;
  int sw = (lane & 7) << 4;                        // XOR bank swizzle (row&7 == lane&7)

  __shared__ u16 k_lds[2 * 64 * 256];              // 64 KB: 2 x [key][n] swizzled
  __shared__ u16 v_lds[2 * 64 * 64];               // 16 KB: 2 x [vq][key] swizzled
  char* kl = (char*)k_lds;
  char* vl = (char*)v_lds;

  int qrow = qi * 128 + w * 32 + l31;

  const char* Kg = (const char*)(Kb + (size_t)b * SS * NN);
  const char* Vg = (const char*)(Vt + (size_t)bh * QQ * SS);

  // staging source offsets (inverse-swizzled global so linear DMA lands swizzled)
  int koffK[8], koffV[2];
  #pragma unroll
  for (int c = 0; c < 8; c++){
    int x = c * 4096 + w * 1024 + lane * 16;
    koffK[c] = x ^ (((x >> 9) & 7) << 4);
  }
  #pragma unroll
  for (int c = 0; c < 2; c++){
    int x = c * 4096 + w * 1024 + lane * 16;       // < 8192
    int vq = x >> 7, ko = x & 127;
    koffV[c] = vq * 8192 + (ko ^ ((vq & 7) << 4));
  }
  // ds_read offsets (loop-invariant VGPRs; buffer/tile selected by imm offset)
  int kOff[16], vOff[4];
  #pragma unroll
  for (int ks = 0; ks < 16; ks++) kOff[ks] = l31 * 512 + ((ks * 32 + hi16) ^ sw);
  #pragma unroll
  for (int c = 0; c < 4; c++) vOff[c] = l31 * 128 + ((c * 32 + hi16) ^ sw);

#define STAGE(kt_, CUR_) do {                                              \
    const char* kg_ = Kg + (size_t)(kt_) * 32768;                          \
    const char* vg_ = Vg + (size_t)(kt_) * 128;                            \
    _Pragma("unroll")                                                      \
    for (int c = 0; c < 8; c++)                                            \
      gload16(kg_ + koffK[c], kl + (CUR_) * 32768 + c * 4096 + w * 1024);  \
    _Pragma("unroll")                                                      \
    for (int c = 0; c < 2; c++)                                            \
      gload16(vg_ + koffV[c], vl + (CUR_) * 8192 + c * 4096 + w * 1024);   \
  } while (0)

  // kick off tile 0 DMA first; XM prologue compute hides its latency
  STAGE(0, 0);

  // --- fused XM prologue: qfr[ks][j] = bf16(Q[qrow][ks*16 + hi*8 + j] * QSCALE) ---
  bf16x8 qfr[16];
  {
    const float QSCALE = 0.015625f * 1.4426950408889634f;  // 1/64 * log2(e)
    const u16* Xp = Kb + ((size_t)b * SS + qrow) * NN + hi * 8;
    bf16x8 xfr[16];
    #pragma unroll
    for (int kk = 0; kk < 16; kk++) xfr[kk] = *(const bf16x8*)(Xp + kk * 16);
    const u16* Mqh = Mq + (size_t)(h * 8) * 8192 + (size_t)lane * 8;
    #pragma unroll
    for (int ct = 0; ct < 8; ct++){
      f32x16 acc = zero16();
      const u16* ap = Mqh + (size_t)ct * 8192;
      #pragma unroll
      for (int kk = 0; kk < 16; kk++)
        acc = MFMA32(*(const bf16x8*)(ap + kk * 512), xfr[kk], acc);
      #pragma unroll
      for (int i = 0; i < 16; i++) acc[i] *= QSCALE;
      {
        unsigned a0 = pkbf(acc[0], acc[1]),  b0 = pkbf(acc[2], acc[3]);
        unsigned c0 = pkbf(acc[4], acc[5]),  d0 = pkbf(acc[6], acc[7]);
        asm("v_permlane32_swap_b32 %0, %1" : "+v"(a0), "+v"(c0));
        asm("v_permlane32_swap_b32 %0, %1" : "+v"(b0), "+v"(d0));
        union { bf16x8 v; unsigned u[4]; } u0;
        u0.u[0] = a0; u0.u[1] = b0; u0.u[2] = c0; u0.u[3] = d0;
        qfr[2 * ct] = u0.v;
      }
      {
        unsigned a1 = pkbf(acc[8], acc[9]),   b1 = pkbf(acc[10], acc[11]);
        unsigned c1 = pkbf(acc[12], acc[13]), d1 = pkbf(acc[14], acc[15]);
        asm("v_permlane32_swap_b32 %0, %1" : "+v"(a1), "+v"(c1));
        asm("v_permlane32_swap_b32 %0, %1" : "+v"(b1), "+v"(d1));
        union { bf16x8 v; unsigned u[4]; } u1;
        u1.u[0] = a1; u1.u[1] = b1; u1.u[2] = c1; u1.u[3] = d1;
        qfr[2 * ct + 1] = u1.v;
      }
    }
  }

  f32x16 o0 = zero16(), o1 = zero16();
  float m = -1e30f, l = 0.f;

#define PVSTEP(P, RB, VOFF, VCONST) do {                                   \
    unsigned a_ = pkbf(P[RB+0], P[RB+1]);                                  \
    unsigned b_ = pkbf(P[RB+2], P[RB+3]);                                  \
    unsigned c_ = pkbf(P[RB+4], P[RB+5]);                                  \
    unsigned d_ = pkbf(P[RB+6], P[RB+7]);                                  \
    asm("v_permlane32_swap_b32 %0, %1" : "+v"(a_), "+v"(c_));              \
    asm("v_permlane32_swap_b32 %0, %1" : "+v"(b_), "+v"(d_));              \
    union { bf16x8 v; unsigned u[4]; } pu_;                                \
    pu_.u[0] = a_; pu_.u[1] = b_; pu_.u[2] = c_; pu_.u[3] = d_;            \
    bf16x8 vf0_ = *(const bf16x8*)(vl + (VOFF) + (VCONST));                \
    bf16x8 vf1_ = *(const bf16x8*)(vl + (VOFF) + (VCONST) + 4096);         \
    o0 = MFMA32(pu_.v, vf0_, o0);                                          \
    o1 = MFMA32(pu_.v, vf1_, o1);                                          \
  } while (0)

#define ITER(kt_, CUR_, LAST_) do {                                        \
    if (!(LAST_)) STAGE((kt_) + 1, (CUR_) ^ 1);                            \
    if (LAST_) { asm volatile("s_waitcnt vmcnt(0)" ::: "memory"); }        \
    else       { asm volatile("s_waitcnt vmcnt(10)" ::: "memory"); }       \
    __builtin_amdgcn_sched_barrier(0);                                     \
    __builtin_amdgcn_s_barrier();                                          \
    __builtin_amdgcn_sched_barrier(0);                                     \
    f32x16 p0 = zero16(), p1 = zero16();                                   \
    __builtin_amdgcn_s_setprio(1);                                         \
    _Pragma("unroll")                                                      \
    for (int ks = 0; ks < 16; ks++){                                       \
      bf16x8 k0 = *(const bf16x8*)(kl + (CUR_) * 32768 + kOff[ks]);        \
      bf16x8 k1 = *(const bf16x8*)(kl + (CUR_) * 32768 + kOff[ks] + 16384);\
      p0 = MFMA32(k0, qfr[ks], p0);                                        \
      p1 = MFMA32(k1, qfr[ks], p1);                                        \
    }                                                                      \
    __builtin_amdgcn_s_setprio(0);                                         \
    /* row max: in-register tree + cross-half shfl (NOT self-permlane) */  \
    float r_[16];                                                          \
    _Pragma("unroll")                                                      \
    for (int i = 0; i < 16; i++) r_[i] = fmaxf(p0[i], p1[i]);              \
    _Pragma("unroll")                                                      \
    for (int i = 0; i < 8; i++) r_[i] = fmaxf(r_[i], r_[i + 8]);           \
    _Pragma("unroll")                                                      \
    for (int i = 0; i < 4; i++) r_[i] = fmaxf(r_[i], r_[i + 4]);           \
    float pm = fmaxf(fmaxf(r_[0], r_[1]), fmaxf(r_[2], r_[3]));            \
    pm = fmaxf(pm, __shfl_xor(pm, 32));                                    \
    if (__any(pm > m + 8.0f)){                 /* defer-max (T13) */       \
      float mn_ = fmaxf(m, pm);                                            \
      float fs_ = exp2f(m - mn_);                                          \
      m = mn_; l *= fs_;                                                   \
      _Pragma("unroll")                                                    \
      for (int i = 0; i < 16; i++){                                        \
        int q_ = (i & 3) + 8 * (i >> 2) + 4 * hi;                          \
        float fv_ = __int_as_float(__builtin_amdgcn_ds_bpermute(           \
                        q_ << 2, __float_as_int(fs_)));                    \
        o0[i] *= fv_; o1[i] *= fv_;                                        \
      }                                                                    \
    }                                                                      \
    _Pragma("unroll")                                                      \
    for (int i = 0; i < 16; i++){                                          \
      p0[i] = exp2f(p0[i] - m);                                            \
      p1[i] = exp2f(p1[i] - m);                                            \
    }                                                                      \
    { float s_[16];                                                        \
      _Pragma("unroll")                                                    \
      for (int i = 0; i < 16; i++) s_[i] = p0[i] + p1[i];                  \
      _Pragma("unroll")                                                    \
      for (int i = 0; i < 8; i++) s_[i] += s_[i + 8];                      \
      _Pragma("unroll")                                                    \
      for (int i = 0; i < 4; i++) s_[i] += s_[i + 4];                      \
      float ps_ = (s_[0] + s_[1]) + (s_[2] + s_[3]);                       \
      ps_ += __shfl_xor(ps_, 32);                                          \
      l += ps_; }                                                          \
    __builtin_amdgcn_s_setprio(1);                                         \
    PVSTEP(p0, 0, vOff[0], (CUR_) * 8192);                                 \
    PVSTEP(p0, 8, vOff[1], (CUR_) * 8192);                                 \
    PVSTEP(p1, 0, vOff[2], (CUR_) * 8192);                                 \
    PVSTEP(p1, 8, vOff[3], (CUR_) * 8192);                                 \
    __builtin_amdgcn_s_setprio(0);                                         \
    __builtin_amdgcn_s_barrier();                                          \
    __builtin_amdgcn_sched_barrier(0);                                     \
  } while (0)

  for (int kt2 = 0; kt2 < 31; kt2++){
    ITER(2 * kt2,     0, 0);
    ITER(2 * kt2 + 1, 1, 0);
  }
  ITER(62, 0, 0);
  ITER(63, 1, 1);
#undef ITER
#undef PVSTEP
#undef STAGE

  // epilogue: normalize by 1/l (broadcast via ds_bpermute), write Zc bf16
  float inv = 1.0f / l;
  u16* Op = Zc + ((size_t)b * SS + qi * 128 + w * 32) * (HH * QQ) + h * QQ;
  #pragma unroll
  for (int i = 0; i < 16; i++){
    int q = (i & 3) + 8 * (i >> 2) + 4 * hi;
    float fv = __int_as_float(__builtin_amdgcn_ds_bpermute(q << 2, __float_as_int(inv)));
    u16* row = Op + (size_t)q * (HH * QQ);
    row[l31]      = f2bf(o0[i] * fv);
    row[32 + l31] = f2bf(o1[i] * fv);
  }
}

// ---------------- out = Zc @ W0 (fp32 out) ----------------
__global__ __launch_bounds__(256) void out_kernel(const u16* __restrict__ Zc,
                                                  const u16* __restrict__ W0t,
                                                  float* __restrict__ out){
  int rbase = blockIdx.x * 64, cbase = blockIdx.y * 128;
  int lane = threadIdx.x & 63, w = threadIdx.x >> 6;
  int lr = lane & 15, g = lane >> 4, lk = g * 8;

  const u16* Ap = Zc + (size_t)(rbase + w * 16 + lr) * ZZ + lk;
  f32x4 acc[8];
  #pragma unroll
  for (int n = 0; n < 8; n++) acc[n] = fzero();

  for (int ks = 0; ks < 16; ks++){
    bf16x8 afr = *(const bf16x8*)(Ap + 32 * ks);
    #pragma unroll
    for (int n = 0; n < 8; n++){
      const u16* bp = W0t + (size_t)(cbase + n * 16 + lr) * ZZ + lk + 32 * ks;
      acc[n] = MFMA16(afr, *(const bf16x8*)bp, acc[n]);
    }
  }
  float* Op = out + (size_t)(rbase + w * 16 + g * 4) * ZZ + cbase;
  #pragma unroll
  for (int n = 0; n < 8; n++)
    #pragma unroll
    for (int r = 0; r < 4; r++)
      Op[(size_t)r * ZZ + n * 16 + lr] = acc[n][r];
}

extern "C" void kernel_launch(void* const* d_in, const int* in_sizes, int n_in,
                              void* d_out, int out_size, void* d_ws, size_t ws_size,
                              hipStream_t stream){
  (void)in_sizes; (void)n_in; (void)out_size; (void)ws_size;
  const float* X  = (const float*)d_in[0];   // [B,S,N]
  const float* M  = (const float*)d_in[1];   // [H,N,N]
  const float* Wv = (const float*)d_in[2];   // [H,N,Q]
  const float* W0 = (const float*)d_in[3];   // [H*Q,Z]
  float* out = (float*)d_out;                // [B,S,Z] fp32

  char* ws = (char*)d_ws;
  size_t off = 0;
  auto alloc = [&](size_t bytes) -> void* {
    void* p = ws + off; off += (bytes + 255) & ~(size_t)255; return p;
  };
  u16* Kb  = (u16*)alloc((size_t)BB * SS * NN * 2);        // X as bf16
  u16* Vtb = (u16*)alloc((size_t)BB * HH * QQ * SS * 2);   // V transposed bf16
  u16* Mq  = (u16*)alloc((size_t)HH * NN * NN * 2);        // M fragment-linear bf16
  u16* Wvt = (u16*)alloc((size_t)HH * QQ * NN * 2);
  u16* W0t = (u16*)alloc((size_t)ZZ * ZZ * 2);
  u16* Zc  = (u16*)alloc((size_t)BB * SS * HH * QQ * 2);

  prep_kernel<<<dim3(2496), dim3(256), 0, stream>>>(X, M, Wv, W0, Kb, Mq, Wvt, W0t);
  vt_kernel<<<dim3(SS/256, BB*HH), dim3(256), 0, stream>>>(Kb, Wvt, Vtb);
  attn_kernel<<<dim3(512), dim3(256), 0, stream>>>(Mq, Kb, Vtb, Zc);
  out_kernel<<<dim3(BB*SS/64, ZZ/128), dim3(256), 0, stream>>>(Zc, W0t, out);
}